// Round 13
// baseline (174.667 us; speedup 1.0000x reference)
//
#include <hip/hip_runtime.h>
#include <hip/hip_bf16.h>
#include <cstdint>
#include <cmath>

// MultiHeadAttention_38946763440365 : B=4 S=2048 D=1024 H=16 DQ=DV=64
// prep (LN + 3 weight-transposes) -> QKV gemm (128^2, V transposed in-epilogue)
// -> flash attention (swapped-QK in-register softmax, 64 q-rows/wave,
// bh%8==XCD remap) -> out gemm (+bias+residual).
// Workspace map (bytes):
//   [0,16M)    ln    bf16 [8192][1024]   (also the residual)
//   [16M,64M)  qkv   bf16 [8192][3072]   (Q | K | V-part unused)
//   [64M,80M)  vt    bf16 [64][64][2048] (V transposed per (b,h): [dv][s])
//   [80M,96M)  ctx   bf16 [8192][1024]
//   [96M,102M) wt    bf16 [3072][1024]   (Wq^T | Wkv^T)
//   [102M,104M)wot   bf16 [1024][1024]   (Wo^T)

#define DEV static __device__ __forceinline__

typedef float  f32x4 __attribute__((ext_vector_type(4)));
typedef short  s16x8 __attribute__((ext_vector_type(8)));
typedef short  s16x4 __attribute__((ext_vector_type(4)));
typedef __bf16 bf16x8 __attribute__((ext_vector_type(8)));
typedef unsigned int u32x4 __attribute__((ext_vector_type(4)));

DEV void gload_lds16(const void* g, void* l) {
  __builtin_amdgcn_global_load_lds(
      (const __attribute__((address_space(1))) unsigned int*)g,
      (__attribute__((address_space(3))) unsigned int*)l, 16, 0, 0);
}

DEV bf16x8 ldsv(const void* p) {
  return __builtin_bit_cast(bf16x8, *(const s16x8*)p);
}

DEV f32x4 mfma16(bf16x8 a, bf16x8 b, f32x4 c) {
  return __builtin_amdgcn_mfma_f32_16x16x32_bf16(a, b, c, 0, 0, 0);
}

DEV unsigned short f2b(float f) {
  __hip_bfloat16 h = __float2bfloat16(f);
  return __builtin_bit_cast(unsigned short, h);
}

DEV unsigned int cvt_pk_bf16(float lo, float hi) {
  unsigned int r;
  asm("v_cvt_pk_bf16_f32 %0, %1, %2" : "=v"(r) : "v"(lo), "v"(hi));
  return r;
}

#define MEMFENCE asm volatile("" ::: "memory")

// ---------------------------- prep: LN rows (bid<8192) + weight transposes
__global__ __launch_bounds__(256) void prep_kernel(
    const float* __restrict__ x, const float* __restrict__ gamma,
    const float* __restrict__ beta, __hip_bfloat16* __restrict__ lnout,
    const float* __restrict__ Wq, const float* __restrict__ Wkv,
    const float* __restrict__ Wo,
    __hip_bfloat16* __restrict__ wt, __hip_bfloat16* __restrict__ wot)
{
  __shared__ float smem[64 * 65];
  const int bid = blockIdx.x, t = threadIdx.x;
  if (bid < 8192) {
    const float4 v = ((const float4*)(x + (size_t)bid * 1024))[t];
    float s = v.x + v.y + v.z + v.w;
    float q = v.x * v.x + v.y * v.y + v.z * v.z + v.w * v.w;
#pragma unroll
    for (int m = 1; m < 64; m <<= 1) { s += __shfl_xor(s, m, 64); q += __shfl_xor(q, m, 64); }
    if ((t & 63) == 0) { smem[t >> 6] = s; smem[4 + (t >> 6)] = q; }
    __syncthreads();
    s = smem[0] + smem[1] + smem[2] + smem[3];
    q = smem[4] + smem[5] + smem[6] + smem[7];
    const float mu = s * (1.f / 1024.f);
    const float var = q * (1.f / 1024.f) - mu * mu;
    const float rs = rsqrtf(var + 1e-3f);
    const float4 g = ((const float4*)gamma)[t];
    const float4 bt = ((const float4*)beta)[t];
    s16x4 o;
    o[0] = (short)f2b((v.x - mu) * rs * g.x + bt.x);
    o[1] = (short)f2b((v.y - mu) * rs * g.y + bt.y);
    o[2] = (short)f2b((v.z - mu) * rs * g.z + bt.z);
    o[3] = (short)f2b((v.w - mu) * rs * g.w + bt.w);
    *(s16x4*)((short*)lnout + (size_t)bid * 1024 + t * 4) = o;
  } else {
    int u = bid - 8192;
    const float* W; int N; __hip_bfloat16* Wt;
    if (u < 256)      { W = Wq;  N = 1024; Wt = wt; }
    else if (u < 768) { W = Wkv; N = 2048; Wt = wt + (size_t)1024 * 1024; u -= 256; }
    else              { W = Wo;  N = 1024; Wt = wot; u -= 768; }
    const int k0 = (u & 15) * 64, n0 = (u >> 4) * 64;
    float (*tile)[65] = (float(*)[65])smem;
#pragma unroll
    for (int p = 0; p < 4; ++p) {
      int r = p * 16 + (t >> 4), c4 = (t & 15) * 4;
      float4 v = *(const float4*)(W + (size_t)(k0 + r) * N + n0 + c4);
      tile[r][c4] = v.x; tile[r][c4 + 1] = v.y; tile[r][c4 + 2] = v.z; tile[r][c4 + 3] = v.w;
    }
    __syncthreads();
#pragma unroll
    for (int p = 0; p < 4; ++p) {
      int n = p * 16 + (t >> 4), kc = (t & 15) * 4;
      s16x4 o;
      o[0] = (short)f2b(tile[kc][n]);     o[1] = (short)f2b(tile[kc + 1][n]);
      o[2] = (short)f2b(tile[kc + 2][n]); o[3] = (short)f2b(tile[kc + 3][n]);
      *(s16x4*)((short*)Wt + (size_t)(n0 + n) * 1024 + k0 + kc) = o;
    }
  }
}

// ------------------------- QKV GEMM: 128^2 m97-structure, XCD-swizzled 1-D grid
// Q/K tiles (col0 < 2048) -> qkv.  V tiles (col0 >= 2048) -> transposed in LDS
// and written straight to vt [bh][dv][s].
__global__ __launch_bounds__(256, 2) void gemm_qkv(
    const __hip_bfloat16* __restrict__ A, const __hip_bfloat16* __restrict__ Bt,
    const float* __restrict__ bias0, const float* __restrict__ bias1,
    __hip_bfloat16* __restrict__ outb, __hip_bfloat16* __restrict__ vt)
{
  __shared__ __align__(16) short smem[2 * 128 * 64];   // sA | sB (32KB)
  short* sA = smem;
  short* sB = smem + 128 * 64;
  const int t = threadIdx.x, l = t & 63, w = t >> 6;
  const int wr = w >> 1, wc = w & 1, lr = l & 15, lg = l >> 4;
  int lin = (int)blockIdx.x;
  lin = (lin & 7) * 192 + (lin >> 3);            // bijective: 1536 = 8 * 192
  const int bx = lin % 24, by = lin / 24;
  const int row0 = by * 128, col0 = bx * 128;
  f32x4 acc[4][4] = {};

  for (int kt = 0; kt < 1024; kt += 64) {
#pragma unroll
    for (int p = 0; p < 4; ++p) {
      const int L = p * 4096 + t * 16;
      const int r = L >> 7, c = ((L >> 4) & 7) ^ (r & 7);
      gload_lds16((const char*)A + ((size_t)(row0 + r) * 1024 + kt + c * 8) * 2, (char*)sA + L);
    }
#pragma unroll
    for (int p = 0; p < 4; ++p) {
      const int L = p * 4096 + t * 16;
      const int r = L >> 7, c = ((L >> 4) & 7) ^ (r & 7);
      gload_lds16((const char*)Bt + ((size_t)(col0 + r) * 1024 + kt + c * 8) * 2, (char*)sB + L);
    }
    __syncthreads();

    bf16x8 af[4][2], bfr[4][2];
#pragma unroll
    for (int mb = 0; mb < 4; ++mb) {
      const int ar = wr * 64 + mb * 16 + lr;
#pragma unroll
      for (int kk = 0; kk < 2; ++kk)
        af[mb][kk] = ldsv((const char*)sA + ar * 128 + (((kk * 4 + lg) ^ (ar & 7)) * 16));
    }
#pragma unroll
    for (int nb = 0; nb < 4; ++nb) {
      const int br = wc * 64 + nb * 16 + lr;
#pragma unroll
      for (int kk = 0; kk < 2; ++kk)
        bfr[nb][kk] = ldsv((const char*)sB + br * 128 + (((kk * 4 + lg) ^ (br & 7)) * 16));
    }
#pragma unroll
    for (int kk = 0; kk < 2; ++kk)
#pragma unroll
      for (int mb = 0; mb < 4; ++mb)
#pragma unroll
        for (int nb = 0; nb < 4; ++nb)
          acc[mb][nb] = mfma16(af[mb][kk], bfr[nb][kk], acc[mb][nb]);
    __syncthreads();
  }

  if (col0 < 2048) {
#pragma unroll
    for (int mb = 0; mb < 4; ++mb) {
      const int rbase = row0 + wr * 64 + mb * 16 + lg * 4;
#pragma unroll
      for (int nb = 0; nb < 4; ++nb) {
        const int col = col0 + wc * 64 + nb * 16 + lr;
        const float bias = (col < 1024) ? bias0[col] : bias1[col - 1024];
#pragma unroll
        for (int jr = 0; jr < 4; ++jr)
          outb[(size_t)(rbase + jr) * 3072 + col] = __float2bfloat16(acc[mb][nb][jr] + bias);
      }
    }
  } else {
#pragma unroll
    for (int mb = 0; mb < 4; ++mb) {
      const int rl = wr * 64 + mb * 16 + lg * 4;
#pragma unroll
      for (int nb = 0; nb < 4; ++nb) {
        const int cl = wc * 64 + nb * 16 + lr;
        const float bias = bias1[col0 + cl - 1024];
        s16x4 pk;
#pragma unroll
        for (int jr = 0; jr < 4; ++jr)
          pk[jr] = (short)f2b(acc[mb][nb][jr] + bias);
        *(s16x4*)(&smem[cl * 128 + (rl ^ ((cl & 7) << 3))]) = pk;
      }
    }
    __syncthreads();
    const int b = row0 >> 11, s_in0 = row0 & 2047;
#pragma unroll
    for (int i = 0; i < 8; ++i) {
      const int cl = i * 16 + (t >> 4);
      const int rc = (t & 15) * 8;
      s16x8 v = *(const s16x8*)(&smem[cl * 128 + (rc ^ ((cl & 7) << 3))]);
      const int vcol = col0 - 2048 + cl;
      const int h = vcol >> 6, dv = vcol & 63;
      *(s16x8*)((short*)vt + ((size_t)((b * 16 + h) * 64 + dv)) * 2048 + s_in0 + rc) = v;
    }
  }
}

// ------------------------------------------------------- GEMM: out proj (+resid)
__global__ __launch_bounds__(256, 2) void gemm_out(
    const __hip_bfloat16* __restrict__ A, const __hip_bfloat16* __restrict__ Bt,
    const float* __restrict__ bias0,
    const __hip_bfloat16* __restrict__ resid, float* __restrict__ outf)
{
  __shared__ __align__(16) short sA[128 * 64];
  __shared__ __align__(16) short sB[128 * 64];
  const int t = threadIdx.x, l = t & 63, w = t >> 6;
  const int wr = w >> 1, wc = w & 1, lr = l & 15, lg = l >> 4;
  const int row0 = blockIdx.y * 128, col0 = blockIdx.x * 128;
  f32x4 acc[4][4] = {};

  for (int kt = 0; kt < 1024; kt += 64) {
#pragma unroll
    for (int p = 0; p < 4; ++p) {
      const int L = p * 4096 + t * 16;
      const int r = L >> 7, c = ((L >> 4) & 7) ^ (r & 7);
      gload_lds16((const char*)A + ((size_t)(row0 + r) * 1024 + kt + c * 8) * 2, (char*)sA + L);
    }
#pragma unroll
    for (int p = 0; p < 4; ++p) {
      const int L = p * 4096 + t * 16;
      const int r = L >> 7, c = ((L >> 4) & 7) ^ (r & 7);
      gload_lds16((const char*)Bt + ((size_t)(col0 + r) * 1024 + kt + c * 8) * 2, (char*)sB + L);
    }
    __syncthreads();

    bf16x8 af[4][2], bfr[4][2];
#pragma unroll
    for (int mb = 0; mb < 4; ++mb) {
      const int ar = wr * 64 + mb * 16 + lr;
#pragma unroll
      for (int kk = 0; kk < 2; ++kk)
        af[mb][kk] = ldsv((const char*)sA + ar * 128 + (((kk * 4 + lg) ^ (ar & 7)) * 16));
    }
#pragma unroll
    for (int nb = 0; nb < 4; ++nb) {
      const int br = wc * 64 + nb * 16 + lr;
#pragma unroll
      for (int kk = 0; kk < 2; ++kk)
        bfr[nb][kk] = ldsv((const char*)sB + br * 128 + (((kk * 4 + lg) ^ (br & 7)) * 16));
    }
#pragma unroll
    for (int kk = 0; kk < 2; ++kk)
#pragma unroll
      for (int mb = 0; mb < 4; ++mb)
#pragma unroll
        for (int nb = 0; nb < 4; ++nb)
          acc[mb][nb] = mfma16(af[mb][kk], bfr[nb][kk], acc[mb][nb]);
    __syncthreads();
  }

#pragma unroll
  for (int mb = 0; mb < 4; ++mb) {
    const int rbase = row0 + wr * 64 + mb * 16 + lg * 4;
#pragma unroll
    for (int nb = 0; nb < 4; ++nb) {
      const int col = col0 + wc * 64 + nb * 16 + lr;
      const float bias = bias0[col];
#pragma unroll
      for (int jr = 0; jr < 4; ++jr) {
        const size_t idx = (size_t)(rbase + jr) * 1024 + col;
        outf[idx] = acc[mb][nb][jr] + bias + __bfloat162float(resid[idx]);
      }
    }
  }
}

// ----------------------------------------------------------- flash attention
// 1-D grid 512: bh%8 == XCD (per-XCD K/V panels fit L2). 4 waves x 64 q-rows
// (mbt=4: K/V fragments, staging, and barriers amortized over 2x MFMA).
// KVBLK=64; swapped-QK in-register softmax (verified body, parameterized).
__global__ __launch_bounds__(256, 2) void attn_kernel(
    const __hip_bfloat16* __restrict__ qkv, const __hip_bfloat16* __restrict__ vt,
    const int* __restrict__ lens, __hip_bfloat16* __restrict__ ctx)
{
  __shared__ __align__(16) short sall[18432];   // K dbuf | V dbuf | epilogue reuse
  const int t = threadIdx.x, l = t & 63, w = t >> 6;
  const int lr = l & 15, lg = l >> 4;
  const int bid = blockIdx.x;
  const int xcd = bid & 7, j = bid >> 3;
  const int bh = ((j >> 3) << 3) | xcd;          // bh % 8 == xcd; bijective
  const int qb = j & 7;
  const int b = bh >> 4, h = bh & 15;
  const int q0 = qb * 256 + w * 64;
  const int len = lens[b];
  const float NEG = -__builtin_inff();
  const float QSC = 0.18033688f;  // 0.125 * log2(e)

  bf16x8 qf[4][2];
#pragma unroll
  for (int mbt = 0; mbt < 4; ++mbt)
#pragma unroll
    for (int kk = 0; kk < 2; ++kk) {
      bf16x8 r = ldsv((const char*)qkv +
          ((size_t)(b * 2048 + q0 + mbt * 16 + lr) * 3072 + h * 64 + kk * 32 + lg * 8) * 2);
#pragma unroll
      for (int e = 0; e < 8; ++e) qf[mbt][kk][e] = (__bf16)((float)r[e] * QSC);
    }

  f32x4 o[4][4] = {};                  // o[nbt2][mbt]
  float mrun[4] = {NEG, NEG, NEG, NEG}, ssum[4] = {0.f, 0.f, 0.f, 0.f};

  auto stage = [&](short* dK, short* dV, int kv0) {
#pragma unroll
    for (int p = 0; p < 2; ++p) {
      const int L = p * 4096 + t * 16;
      const int r = L >> 7, c = ((L >> 4) & 7) ^ (r & 7);
      gload_lds16((const char*)qkv +
          ((size_t)(b * 2048 + kv0 + r) * 3072 + 1024 + h * 64 + c * 8) * 2, (char*)dK + L);
    }
#pragma unroll
    for (int p = 0; p < 2; ++p) {
      const int L = p * 4096 + t * 16;
      const int r = L >> 7, c = ((L >> 4) & 7) ^ (r & 7);
      gload_lds16((const char*)vt +
          ((size_t)(bh * 64 + r) * 2048 + kv0 + c * 8) * 2, (char*)dV + L);
    }
  };

  const int nt = (len + 63) >> 6;
  short* curK = sall;          short* nxtK = sall + 4096;
  short* curV = sall + 8192;   short* nxtV = sall + 12288;
  stage(curK, curV, 0);

  const int srcA = (lg & 1) * 32 + lr;
  const int srcB = srcA + 16;

  for (int ti = 0; ti < nt; ++ti) {
    const int kv0 = ti * 64;
    if (ti + 1 < nt) {
      stage(nxtK, nxtV, kv0 + 64);
      asm volatile("s_waitcnt vmcnt(4)" ::: "memory");
    } else {
      asm volatile("s_waitcnt vmcnt(0)" ::: "memory");
    }
    MEMFENCE; __builtin_amdgcn_s_barrier(); MEMFENCE;

    f32x4 sf[4][4] = {};
    __builtin_amdgcn_s_setprio(1);
#pragma unroll
    for (int kk = 0; kk < 2; ++kk) {
      bf16x8 ak[4];
#pragma unroll
      for (int nbt = 0; nbt < 4; ++nbt) {
        const int br = nbt * 16 + lr;
        ak[nbt] = ldsv((const char*)curK + br * 128 + (((kk * 4 + lg) ^ (br & 7)) * 16));
      }
#pragma unroll
      for (int mbt = 0; mbt < 4; ++mbt)
#pragma unroll
        for (int nbt = 0; nbt < 4; ++nbt)
          sf[mbt][nbt] = mfma16(ak[nbt], qf[mbt][kk], sf[mbt][nbt]);
    }
    __builtin_amdgcn_s_setprio(0);

    if (kv0 + 64 > len) {
#pragma unroll
      for (int nbt = 0; nbt < 4; ++nbt)
#pragma unroll
        for (int jr = 0; jr < 4; ++jr)
          if (kv0 + nbt * 16 + lg * 4 + jr >= len) {
#pragma unroll
            for (int mbt = 0; mbt < 4; ++mbt)
              sf[mbt][nbt][jr] = NEG;
          }
    }

    float rm[4];
#pragma unroll
    for (int mbt = 0; mbt < 4; ++mbt) {
      f32x4 m4 = sf[mbt][0];
      m4 = __builtin_elementwise_max(m4, sf[mbt][1]);
      m4 = __builtin_elementwise_max(m4, sf[mbt][2]);
      m4 = __builtin_elementwise_max(m4, sf[mbt][3]);
      float m0 = fmaxf(fmaxf(m4[0], m4[1]), fmaxf(m4[2], m4[3]));
      m0 = fmaxf(m0, __shfl_xor(m0, 16, 64));
      m0 = fmaxf(m0, __shfl_xor(m0, 32, 64));
      rm[mbt] = m0;
    }
    const bool need = (rm[0] > mrun[0] + 3.f) || (rm[1] > mrun[1] + 3.f) ||
                      (rm[2] > mrun[2] + 3.f) || (rm[3] > mrun[3] + 3.f);
    if (__any(need)) {
#pragma unroll
      for (int mbt = 0; mbt < 4; ++mbt) {
        const float mnew = fmaxf(mrun[mbt], rm[mbt]);
        const float corr = __builtin_amdgcn_exp2f(mrun[mbt] - mnew);
        mrun[mbt] = mnew;
        ssum[mbt] *= corr;
#pragma unroll
        for (int nbt2 = 0; nbt2 < 4; ++nbt2) o[nbt2][mbt] *= corr;
      }
    }
    unsigned int W0[4][4], W1[4][4];
#pragma unroll
    for (int mbt = 0; mbt < 4; ++mbt) {
      f32x4 ts = {0.f, 0.f, 0.f, 0.f};
#pragma unroll
      for (int nbt = 0; nbt < 4; ++nbt) {
        f32x4 pe;
#pragma unroll
        for (int jr = 0; jr < 4; ++jr)
          pe[jr] = __builtin_amdgcn_exp2f(sf[mbt][nbt][jr] - mrun[mbt]);
        ts += pe;
        W0[mbt][nbt] = cvt_pk_bf16(pe[0], pe[1]);
        W1[mbt][nbt] = cvt_pk_bf16(pe[2], pe[3]);
      }
      ssum[mbt] += (ts[0] + ts[1]) + (ts[2] + ts[3]);
    }

#pragma unroll
    for (int c = 0; c < 2; ++c) {
      bf16x8 vf[4], pb[4];
#pragma unroll
      for (int nbt2 = 0; nbt2 < 4; ++nbt2) {
        const int vr = nbt2 * 16 + lr;
        vf[nbt2] = ldsv((const char*)curV + vr * 128 + (((c * 4 + lg) ^ (vr & 7)) * 16));
      }
#pragma unroll
      for (int mbt = 0; mbt < 4; ++mbt) {
        const unsigned int selW0 = (lg & 2) ? W0[mbt][2 * c + 1] : W0[mbt][2 * c];
        const unsigned int selW1 = (lg & 2) ? W1[mbt][2 * c + 1] : W1[mbt][2 * c];
        u32x4 bw;
        bw[0] = __shfl((int)selW0, srcA, 64);
        bw[1] = __shfl((int)selW1, srcA, 64);
        bw[2] = __shfl((int)selW0, srcB, 64);
        bw[3] = __shfl((int)selW1, srcB, 64);
        pb[mbt] = __builtin_bit_cast(bf16x8, bw);
      }
      __builtin_amdgcn_s_setprio(1);
#pragma unroll
      for (int nbt2 = 0; nbt2 < 4; ++nbt2)
#pragma unroll
        for (int mbt = 0; mbt < 4; ++mbt)
          o[nbt2][mbt] = mfma16(vf[nbt2], pb[mbt], o[nbt2][mbt]);
      __builtin_amdgcn_s_setprio(0);
    }

    asm volatile("s_waitcnt lgkmcnt(0)" ::: "memory");
    MEMFENCE; __builtin_amdgcn_s_barrier(); MEMFENCE;
    short* tk = curK; curK = nxtK; nxtK = tk;
    short* tv = curV; curV = nxtV; nxtV = tv;
  }

  float inv[4];
#pragma unroll
  for (int mbt = 0; mbt < 4; ++mbt) {
    float s = ssum[mbt];
    s += __shfl_xor(s, 16, 64);
    s += __shfl_xor(s, 32, 64);
    inv[mbt] = 1.f / s;
  }
  char* eb = (char*)sall + w * 8704;   // 64 rows x 68 shorts (136 B stride)
#pragma unroll
  for (int mbt = 0; mbt < 4; ++mbt)
#pragma unroll
    for (int nbt2 = 0; nbt2 < 4; ++nbt2)
#pragma unroll
      for (int jr = 0; jr < 4; ++jr)
        *(short*)(eb + (mbt * 16 + lr) * 136 + (nbt2 * 16 + lg * 4 + jr) * 2) =
            (short)f2b(o[nbt2][mbt][jr] * inv[mbt]);
  asm volatile("s_waitcnt lgkmcnt(0)" ::: "memory");
  __builtin_amdgcn_sched_barrier(0);
#pragma unroll
  for (int hh = 0; hh < 2; ++hh) {
    const int qi = hh * 32 + (l >> 1), half = l & 1;
#pragma unroll
    for (int i = 0; i < 4; ++i) {
      s16x8 v = *(const s16x8*)(eb + qi * 136 + half * 64 + i * 16);
      *(s16x8*)((short*)ctx + (size_t)(b * 2048 + q0 + qi) * 1024 + h * 64 + half * 32 + i * 8) = v;
    }
  }
}

// ------------------------------------------------------------------- launch
extern "C" void kernel_launch(void* const* d_in, const int* in_sizes, int n_in,
                              void* d_out, int out_size, void* d_ws, size_t ws_size,
                              hipStream_t stream)
{
  const float* x     = (const float*)d_in[0];
  const int*   lens  = (const int*)d_in[2];
  const float* Wq    = (const float*)d_in[3];
  const float* bq    = (const float*)d_in[4];
  const float* Wkv   = (const float*)d_in[5];
  const float* bkv   = (const float*)d_in[6];
  const float* Wo    = (const float*)d_in[7];
  const float* bo    = (const float*)d_in[8];
  const float* gamma = (const float*)d_in[9];
  const float* beta  = (const float*)d_in[10];
  float* out = (float*)d_out;

  char* ws = (char*)d_ws;
  __hip_bfloat16* ln  = (__hip_bfloat16*)(ws);
  __hip_bfloat16* qkv = (__hip_bfloat16*)(ws + ((size_t)16 << 20));
  __hip_bfloat16* vt  = (__hip_bfloat16*)(ws + ((size_t)64 << 20));
  __hip_bfloat16* ctx = (__hip_bfloat16*)(ws + ((size_t)80 << 20));
  __hip_bfloat16* wt  = (__hip_bfloat16*)(ws + ((size_t)96 << 20));
  __hip_bfloat16* wot = (__hip_bfloat16*)(ws + ((size_t)102 << 20));

  prep_kernel<<<dim3(9216), dim3(256), 0, stream>>>(
      x, gamma, beta, ln, Wq, Wkv, Wo, wt, wot);
  gemm_qkv<<<dim3(1536), dim3(256), 0, stream>>>(ln, wt, bq, bkv, qkv, vt);
  attn_kernel<<<dim3(512), dim3(256), 0, stream>>>(qkv, vt, lens, ctx);
  gemm_out<<<dim3(8, 64), dim3(256), 0, stream>>>(ctx, wot, bo, ln, out);
}

// Round 14
// 158.279 us; speedup vs baseline: 1.1035x; 1.1035x over previous
//
#include <hip/hip_runtime.h>
#include <hip/hip_bf16.h>
#include <cstdint>
#include <cmath>

// MultiHeadAttention_38946763440365 : B=4 S=2048 D=1024 H=16 DQ=DV=64
// prep (LN + 3 weight-transposes) -> QKV gemm (128^2, V transposed in-epilogue)
// -> flash attention (swapped-QK in-register softmax, 32 q-rows/wave,
// bh%8==XCD remap, 4 blocks/CU) -> out gemm (+bias+residual, XCD-swizzled).
// Session law (R4/R5/R6/R13): co-residency >= 4 blocks/CU beats per-block
// efficiency for barrier-synced kernels on this chip.
// Workspace map (bytes):
//   [0,16M)    ln    bf16 [8192][1024]   (also the residual)
//   [16M,64M)  qkv   bf16 [8192][3072]   (Q | K | V-part unused)
//   [64M,80M)  vt    bf16 [64][64][2048] (V transposed per (b,h): [dv][s])
//   [80M,96M)  ctx   bf16 [8192][1024]
//   [96M,102M) wt    bf16 [3072][1024]   (Wq^T | Wkv^T)
//   [102M,104M)wot   bf16 [1024][1024]   (Wo^T)

#define DEV static __device__ __forceinline__

typedef float  f32x4 __attribute__((ext_vector_type(4)));
typedef short  s16x8 __attribute__((ext_vector_type(8)));
typedef short  s16x4 __attribute__((ext_vector_type(4)));
typedef __bf16 bf16x8 __attribute__((ext_vector_type(8)));
typedef unsigned int u32x4 __attribute__((ext_vector_type(4)));

DEV void gload_lds16(const void* g, void* l) {
  __builtin_amdgcn_global_load_lds(
      (const __attribute__((address_space(1))) unsigned int*)g,
      (__attribute__((address_space(3))) unsigned int*)l, 16, 0, 0);
}

DEV bf16x8 ldsv(const void* p) {
  return __builtin_bit_cast(bf16x8, *(const s16x8*)p);
}

DEV f32x4 mfma16(bf16x8 a, bf16x8 b, f32x4 c) {
  return __builtin_amdgcn_mfma_f32_16x16x32_bf16(a, b, c, 0, 0, 0);
}

DEV unsigned short f2b(float f) {
  __hip_bfloat16 h = __float2bfloat16(f);
  return __builtin_bit_cast(unsigned short, h);
}

DEV unsigned int cvt_pk_bf16(float lo, float hi) {
  unsigned int r;
  asm("v_cvt_pk_bf16_f32 %0, %1, %2" : "=v"(r) : "v"(lo), "v"(hi));
  return r;
}

#define MEMFENCE asm volatile("" ::: "memory")

// ---------------------------- prep: LN rows (bid<8192) + weight transposes
__global__ __launch_bounds__(256) void prep_kernel(
    const float* __restrict__ x, const float* __restrict__ gamma,
    const float* __restrict__ beta, __hip_bfloat16* __restrict__ lnout,
    const float* __restrict__ Wq, const float* __restrict__ Wkv,
    const float* __restrict__ Wo,
    __hip_bfloat16* __restrict__ wt, __hip_bfloat16* __restrict__ wot)
{
  __shared__ float smem[64 * 65];
  const int bid = blockIdx.x, t = threadIdx.x;
  if (bid < 8192) {
    const float4 v = ((const float4*)(x + (size_t)bid * 1024))[t];
    float s = v.x + v.y + v.z + v.w;
    float q = v.x * v.x + v.y * v.y + v.z * v.z + v.w * v.w;
#pragma unroll
    for (int m = 1; m < 64; m <<= 1) { s += __shfl_xor(s, m, 64); q += __shfl_xor(q, m, 64); }
    if ((t & 63) == 0) { smem[t >> 6] = s; smem[4 + (t >> 6)] = q; }
    __syncthreads();
    s = smem[0] + smem[1] + smem[2] + smem[3];
    q = smem[4] + smem[5] + smem[6] + smem[7];
    const float mu = s * (1.f / 1024.f);
    const float var = q * (1.f / 1024.f) - mu * mu;
    const float rs = rsqrtf(var + 1e-3f);
    const float4 g = ((const float4*)gamma)[t];
    const float4 bt = ((const float4*)beta)[t];
    s16x4 o;
    o[0] = (short)f2b((v.x - mu) * rs * g.x + bt.x);
    o[1] = (short)f2b((v.y - mu) * rs * g.y + bt.y);
    o[2] = (short)f2b((v.z - mu) * rs * g.z + bt.z);
    o[3] = (short)f2b((v.w - mu) * rs * g.w + bt.w);
    *(s16x4*)((short*)lnout + (size_t)bid * 1024 + t * 4) = o;
  } else {
    int u = bid - 8192;
    const float* W; int N; __hip_bfloat16* Wt;
    if (u < 256)      { W = Wq;  N = 1024; Wt = wt; }
    else if (u < 768) { W = Wkv; N = 2048; Wt = wt + (size_t)1024 * 1024; u -= 256; }
    else              { W = Wo;  N = 1024; Wt = wot; u -= 768; }
    const int k0 = (u & 15) * 64, n0 = (u >> 4) * 64;
    float (*tile)[65] = (float(*)[65])smem;
#pragma unroll
    for (int p = 0; p < 4; ++p) {
      int r = p * 16 + (t >> 4), c4 = (t & 15) * 4;
      float4 v = *(const float4*)(W + (size_t)(k0 + r) * N + n0 + c4);
      tile[r][c4] = v.x; tile[r][c4 + 1] = v.y; tile[r][c4 + 2] = v.z; tile[r][c4 + 3] = v.w;
    }
    __syncthreads();
#pragma unroll
    for (int p = 0; p < 4; ++p) {
      int n = p * 16 + (t >> 4), kc = (t & 15) * 4;
      s16x4 o;
      o[0] = (short)f2b(tile[kc][n]);     o[1] = (short)f2b(tile[kc + 1][n]);
      o[2] = (short)f2b(tile[kc + 2][n]); o[3] = (short)f2b(tile[kc + 3][n]);
      *(s16x4*)((short*)Wt + (size_t)(n0 + n) * 1024 + k0 + kc) = o;
    }
  }
}

// ------------------------- QKV GEMM: 128^2 m97-structure, XCD-swizzled 1-D grid
// Q/K tiles (col0 < 2048) -> qkv.  V tiles (col0 >= 2048) -> transposed in LDS
// and written straight to vt [bh][dv][s].
__global__ __launch_bounds__(256, 2) void gemm_qkv(
    const __hip_bfloat16* __restrict__ A, const __hip_bfloat16* __restrict__ Bt,
    const float* __restrict__ bias0, const float* __restrict__ bias1,
    __hip_bfloat16* __restrict__ outb, __hip_bfloat16* __restrict__ vt)
{
  __shared__ __align__(16) short smem[2 * 128 * 64];   // sA | sB (32KB)
  short* sA = smem;
  short* sB = smem + 128 * 64;
  const int t = threadIdx.x, l = t & 63, w = t >> 6;
  const int wr = w >> 1, wc = w & 1, lr = l & 15, lg = l >> 4;
  int lin = (int)blockIdx.x;
  lin = (lin & 7) * 192 + (lin >> 3);            // bijective: 1536 = 8 * 192
  const int bx = lin % 24, by = lin / 24;
  const int row0 = by * 128, col0 = bx * 128;
  f32x4 acc[4][4] = {};

  for (int kt = 0; kt < 1024; kt += 64) {
#pragma unroll
    for (int p = 0; p < 4; ++p) {
      const int L = p * 4096 + t * 16;
      const int r = L >> 7, c = ((L >> 4) & 7) ^ (r & 7);
      gload_lds16((const char*)A + ((size_t)(row0 + r) * 1024 + kt + c * 8) * 2, (char*)sA + L);
    }
#pragma unroll
    for (int p = 0; p < 4; ++p) {
      const int L = p * 4096 + t * 16;
      const int r = L >> 7, c = ((L >> 4) & 7) ^ (r & 7);
      gload_lds16((const char*)Bt + ((size_t)(col0 + r) * 1024 + kt + c * 8) * 2, (char*)sB + L);
    }
    __syncthreads();

    bf16x8 af[4][2], bfr[4][2];
#pragma unroll
    for (int mb = 0; mb < 4; ++mb) {
      const int ar = wr * 64 + mb * 16 + lr;
#pragma unroll
      for (int kk = 0; kk < 2; ++kk)
        af[mb][kk] = ldsv((const char*)sA + ar * 128 + (((kk * 4 + lg) ^ (ar & 7)) * 16));
    }
#pragma unroll
    for (int nb = 0; nb < 4; ++nb) {
      const int br = wc * 64 + nb * 16 + lr;
#pragma unroll
      for (int kk = 0; kk < 2; ++kk)
        bfr[nb][kk] = ldsv((const char*)sB + br * 128 + (((kk * 4 + lg) ^ (br & 7)) * 16));
    }
#pragma unroll
    for (int kk = 0; kk < 2; ++kk)
#pragma unroll
      for (int mb = 0; mb < 4; ++mb)
#pragma unroll
        for (int nb = 0; nb < 4; ++nb)
          acc[mb][nb] = mfma16(af[mb][kk], bfr[nb][kk], acc[mb][nb]);
    __syncthreads();
  }

  if (col0 < 2048) {
#pragma unroll
    for (int mb = 0; mb < 4; ++mb) {
      const int rbase = row0 + wr * 64 + mb * 16 + lg * 4;
#pragma unroll
      for (int nb = 0; nb < 4; ++nb) {
        const int col = col0 + wc * 64 + nb * 16 + lr;
        const float bias = (col < 1024) ? bias0[col] : bias1[col - 1024];
#pragma unroll
        for (int jr = 0; jr < 4; ++jr)
          outb[(size_t)(rbase + jr) * 3072 + col] = __float2bfloat16(acc[mb][nb][jr] + bias);
      }
    }
  } else {
#pragma unroll
    for (int mb = 0; mb < 4; ++mb) {
      const int rl = wr * 64 + mb * 16 + lg * 4;
#pragma unroll
      for (int nb = 0; nb < 4; ++nb) {
        const int cl = wc * 64 + nb * 16 + lr;
        const float bias = bias1[col0 + cl - 1024];
        s16x4 pk;
#pragma unroll
        for (int jr = 0; jr < 4; ++jr)
          pk[jr] = (short)f2b(acc[mb][nb][jr] + bias);
        *(s16x4*)(&smem[cl * 128 + (rl ^ ((cl & 7) << 3))]) = pk;
      }
    }
    __syncthreads();
    const int b = row0 >> 11, s_in0 = row0 & 2047;
#pragma unroll
    for (int i = 0; i < 8; ++i) {
      const int cl = i * 16 + (t >> 4);
      const int rc = (t & 15) * 8;
      s16x8 v = *(const s16x8*)(&smem[cl * 128 + (rc ^ ((cl & 7) << 3))]);
      const int vcol = col0 - 2048 + cl;
      const int h = vcol >> 6, dv = vcol & 63;
      *(s16x8*)((short*)vt + ((size_t)((b * 16 + h) * 64 + dv)) * 2048 + s_in0 + rc) = v;
    }
  }
}

// ---------------------- GEMM: out proj (+bias+residual), XCD-swizzled 1-D grid
__global__ __launch_bounds__(256, 2) void gemm_out(
    const __hip_bfloat16* __restrict__ A, const __hip_bfloat16* __restrict__ Bt,
    const float* __restrict__ bias0,
    const __hip_bfloat16* __restrict__ resid, float* __restrict__ outf)
{
  __shared__ __align__(16) short sA[128 * 64];
  __shared__ __align__(16) short sB[128 * 64];
  const int t = threadIdx.x, l = t & 63, w = t >> 6;
  const int wr = w >> 1, wc = w & 1, lr = l & 15, lg = l >> 4;
  int lin = (int)blockIdx.x;
  lin = (lin & 7) * 64 + (lin >> 3);             // bijective: 512 = 8 * 64
  const int row0 = (lin >> 3) * 128, col0 = (lin & 7) * 128;
  f32x4 acc[4][4] = {};

  for (int kt = 0; kt < 1024; kt += 64) {
#pragma unroll
    for (int p = 0; p < 4; ++p) {
      const int L = p * 4096 + t * 16;
      const int r = L >> 7, c = ((L >> 4) & 7) ^ (r & 7);
      gload_lds16((const char*)A + ((size_t)(row0 + r) * 1024 + kt + c * 8) * 2, (char*)sA + L);
    }
#pragma unroll
    for (int p = 0; p < 4; ++p) {
      const int L = p * 4096 + t * 16;
      const int r = L >> 7, c = ((L >> 4) & 7) ^ (r & 7);
      gload_lds16((const char*)Bt + ((size_t)(col0 + r) * 1024 + kt + c * 8) * 2, (char*)sB + L);
    }
    __syncthreads();

    bf16x8 af[4][2], bfr[4][2];
#pragma unroll
    for (int mb = 0; mb < 4; ++mb) {
      const int ar = wr * 64 + mb * 16 + lr;
#pragma unroll
      for (int kk = 0; kk < 2; ++kk)
        af[mb][kk] = ldsv((const char*)sA + ar * 128 + (((kk * 4 + lg) ^ (ar & 7)) * 16));
    }
#pragma unroll
    for (int nb = 0; nb < 4; ++nb) {
      const int br = wc * 64 + nb * 16 + lr;
#pragma unroll
      for (int kk = 0; kk < 2; ++kk)
        bfr[nb][kk] = ldsv((const char*)sB + br * 128 + (((kk * 4 + lg) ^ (br & 7)) * 16));
    }
#pragma unroll
    for (int kk = 0; kk < 2; ++kk)
#pragma unroll
      for (int mb = 0; mb < 4; ++mb)
#pragma unroll
        for (int nb = 0; nb < 4; ++nb)
          acc[mb][nb] = mfma16(af[mb][kk], bfr[nb][kk], acc[mb][nb]);
    __syncthreads();
  }

#pragma unroll
  for (int mb = 0; mb < 4; ++mb) {
    const int rbase = row0 + wr * 64 + mb * 16 + lg * 4;
#pragma unroll
    for (int nb = 0; nb < 4; ++nb) {
      const int col = col0 + wc * 64 + nb * 16 + lr;
      const float bias = bias0[col];
#pragma unroll
      for (int jr = 0; jr < 4; ++jr) {
        const size_t idx = (size_t)(rbase + jr) * 1024 + col;
        outf[idx] = acc[mb][nb][jr] + bias + __bfloat162float(resid[idx]);
      }
    }
  }
}

// ----------------------------------------------------------- flash attention
// R12-verified: 1-D grid 1024 (4 blocks/CU), bh%8 == XCD (per-XCD K/V panels
// fit L2). 4 waves x 32 q-rows; KVBLK=64; swapped-QK in-register softmax.
__global__ __launch_bounds__(256, 4) void attn_kernel(
    const __hip_bfloat16* __restrict__ qkv, const __hip_bfloat16* __restrict__ vt,
    const int* __restrict__ lens, __hip_bfloat16* __restrict__ ctx)
{
  __shared__ __align__(16) short sK[2][64 * 64];
  __shared__ __align__(16) short sV[2][64 * 64];
  const int t = threadIdx.x, l = t & 63, w = t >> 6;
  const int lr = l & 15, lg = l >> 4;
  const int bid = blockIdx.x;
  const int xcd = bid & 7, j = bid >> 3;
  const int bh = ((j >> 4) << 3) | xcd;          // bh % 8 == xcd; bijective
  const int qb = j & 15;
  const int b = bh >> 4, h = bh & 15;
  const int q0 = qb * 128 + w * 32;
  const int len = lens[b];
  const float NEG = -__builtin_inff();
  const float QSC = 0.18033688f;  // 0.125 * log2(e)

  bf16x8 qf[2][2];
#pragma unroll
  for (int mbt = 0; mbt < 2; ++mbt)
#pragma unroll
    for (int kk = 0; kk < 2; ++kk) {
      bf16x8 r = ldsv((const char*)qkv +
          ((size_t)(b * 2048 + q0 + mbt * 16 + lr) * 3072 + h * 64 + kk * 32 + lg * 8) * 2);
#pragma unroll
      for (int e = 0; e < 8; ++e) qf[mbt][kk][e] = (__bf16)((float)r[e] * QSC);
    }

  f32x4 o[4][2] = {};
  float mrun[2] = {NEG, NEG}, ssum[2] = {0.f, 0.f};

  auto stage = [&](short* dK, short* dV, int kv0) {
#pragma unroll
    for (int p = 0; p < 2; ++p) {
      const int L = p * 4096 + t * 16;
      const int r = L >> 7, c = ((L >> 4) & 7) ^ (r & 7);
      gload_lds16((const char*)qkv +
          ((size_t)(b * 2048 + kv0 + r) * 3072 + 1024 + h * 64 + c * 8) * 2, (char*)dK + L);
    }
#pragma unroll
    for (int p = 0; p < 2; ++p) {
      const int L = p * 4096 + t * 16;
      const int r = L >> 7, c = ((L >> 4) & 7) ^ (r & 7);
      gload_lds16((const char*)vt +
          ((size_t)(bh * 64 + r) * 2048 + kv0 + c * 8) * 2, (char*)dV + L);
    }
  };

  const int nt = (len + 63) >> 6;
  short* curK = sK[0]; short* nxtK = sK[1];
  short* curV = sV[0]; short* nxtV = sV[1];
  stage(curK, curV, 0);

  const int srcA = (lg & 1) * 32 + lr;
  const int srcB = srcA + 16;

  for (int ti = 0; ti < nt; ++ti) {
    const int kv0 = ti * 64;
    if (ti + 1 < nt) {
      stage(nxtK, nxtV, kv0 + 64);
      asm volatile("s_waitcnt vmcnt(4)" ::: "memory");
    } else {
      asm volatile("s_waitcnt vmcnt(0)" ::: "memory");
    }
    MEMFENCE; __builtin_amdgcn_s_barrier(); MEMFENCE;

    f32x4 sf[2][4] = {};
    __builtin_amdgcn_s_setprio(1);
#pragma unroll
    for (int kk = 0; kk < 2; ++kk) {
      bf16x8 ak[4];
#pragma unroll
      for (int nbt = 0; nbt < 4; ++nbt) {
        const int br = nbt * 16 + lr;
        ak[nbt] = ldsv((const char*)curK + br * 128 + (((kk * 4 + lg) ^ (br & 7)) * 16));
      }
#pragma unroll
      for (int mbt = 0; mbt < 2; ++mbt)
#pragma unroll
        for (int nbt = 0; nbt < 4; ++nbt)
          sf[mbt][nbt] = mfma16(ak[nbt], qf[mbt][kk], sf[mbt][nbt]);
    }
    __builtin_amdgcn_s_setprio(0);

    if (kv0 + 64 > len) {
#pragma unroll
      for (int nbt = 0; nbt < 4; ++nbt)
#pragma unroll
        for (int jr = 0; jr < 4; ++jr)
          if (kv0 + nbt * 16 + lg * 4 + jr >= len) {
            sf[0][nbt][jr] = NEG;
            sf[1][nbt][jr] = NEG;
          }
    }

    float rm[2];
#pragma unroll
    for (int mbt = 0; mbt < 2; ++mbt) {
      f32x4 m4 = sf[mbt][0];
      m4 = __builtin_elementwise_max(m4, sf[mbt][1]);
      m4 = __builtin_elementwise_max(m4, sf[mbt][2]);
      m4 = __builtin_elementwise_max(m4, sf[mbt][3]);
      float m0 = fmaxf(fmaxf(m4[0], m4[1]), fmaxf(m4[2], m4[3]));
      m0 = fmaxf(m0, __shfl_xor(m0, 16, 64));
      m0 = fmaxf(m0, __shfl_xor(m0, 32, 64));
      rm[mbt] = m0;
    }
    const bool need = (rm[0] > mrun[0] + 3.f) || (rm[1] > mrun[1] + 3.f);
    if (__any(need)) {
#pragma unroll
      for (int mbt = 0; mbt < 2; ++mbt) {
        const float mnew = fmaxf(mrun[mbt], rm[mbt]);
        const float corr = __builtin_amdgcn_exp2f(mrun[mbt] - mnew);
        mrun[mbt] = mnew;
        ssum[mbt] *= corr;
#pragma unroll
        for (int nbt2 = 0; nbt2 < 4; ++nbt2) o[nbt2][mbt] *= corr;
      }
    }
    unsigned int W0[2][4], W1[2][4];
#pragma unroll
    for (int mbt = 0; mbt < 2; ++mbt) {
      f32x4 ts = {0.f, 0.f, 0.f, 0.f};
#pragma unroll
      for (int nbt = 0; nbt < 4; ++nbt) {
        f32x4 pe;
#pragma unroll
        for (int jr = 0; jr < 4; ++jr)
          pe[jr] = __builtin_amdgcn_exp2f(sf[mbt][nbt][jr] - mrun[mbt]);
        ts += pe;
        W0[mbt][nbt] = cvt_pk_bf16(pe[0], pe[1]);
        W1[mbt][nbt] = cvt_pk_bf16(pe[2], pe[3]);
      }
      ssum[mbt] += (ts[0] + ts[1]) + (ts[2] + ts[3]);
    }

#pragma unroll
    for (int c = 0; c < 2; ++c) {
      bf16x8 vf[4], pb[2];
#pragma unroll
      for (int nbt2 = 0; nbt2 < 4; ++nbt2) {
        const int vr = nbt2 * 16 + lr;
        vf[nbt2] = ldsv((const char*)curV + vr * 128 + (((c * 4 + lg) ^ (vr & 7)) * 16));
      }
#pragma unroll
      for (int mbt = 0; mbt < 2; ++mbt) {
        const unsigned int selW0 = (lg & 2) ? W0[mbt][2 * c + 1] : W0[mbt][2 * c];
        const unsigned int selW1 = (lg & 2) ? W1[mbt][2 * c + 1] : W1[mbt][2 * c];
        u32x4 bw;
        bw[0] = __shfl((int)selW0, srcA, 64);
        bw[1] = __shfl((int)selW1, srcA, 64);
        bw[2] = __shfl((int)selW0, srcB, 64);
        bw[3] = __shfl((int)selW1, srcB, 64);
        pb[mbt] = __builtin_bit_cast(bf16x8, bw);
      }
      __builtin_amdgcn_s_setprio(1);
#pragma unroll
      for (int nbt2 = 0; nbt2 < 4; ++nbt2)
#pragma unroll
        for (int mbt = 0; mbt < 2; ++mbt)
          o[nbt2][mbt] = mfma16(vf[nbt2], pb[mbt], o[nbt2][mbt]);
      __builtin_amdgcn_s_setprio(0);
    }

    asm volatile("s_waitcnt lgkmcnt(0)" ::: "memory");
    MEMFENCE; __builtin_amdgcn_s_barrier(); MEMFENCE;
    short* tk = curK; curK = nxtK; nxtK = tk;
    short* tv = curV; curV = nxtV; nxtV = tv;
  }

  float inv[2];
#pragma unroll
  for (int mbt = 0; mbt < 2; ++mbt) {
    float s = ssum[mbt];
    s += __shfl_xor(s, 16, 64);
    s += __shfl_xor(s, 32, 64);
    inv[mbt] = 1.f / s;
  }
  char* eb = (char*)sK + w * 4352;   // 32 rows x 68 shorts (136 B stride)
#pragma unroll
  for (int mbt = 0; mbt < 2; ++mbt)
#pragma unroll
    for (int nbt2 = 0; nbt2 < 4; ++nbt2)
#pragma unroll
      for (int jr = 0; jr < 4; ++jr)
        *(short*)(eb + (mbt * 16 + lr) * 136 + (nbt2 * 16 + lg * 4 + jr) * 2) =
            (short)f2b(o[nbt2][mbt][jr] * inv[mbt]);
  asm volatile("s_waitcnt lgkmcnt(0)" ::: "memory");
  __builtin_amdgcn_sched_barrier(0);
  const int qi = l >> 1, half = l & 1;
#pragma unroll
  for (int i = 0; i < 4; ++i) {
    s16x8 v = *(const s16x8*)(eb + qi * 136 + half * 64 + i * 16);
    *(s16x8*)((short*)ctx + (size_t)(b * 2048 + q0 + qi) * 1024 + h * 64 + half * 32 + i * 8) = v;
  }
}

// ------------------------------------------------------------------- launch
extern "C" void kernel_launch(void* const* d_in, const int* in_sizes, int n_in,
                              void* d_out, int out_size, void* d_ws, size_t ws_size,
                              hipStream_t stream)
{
  const float* x     = (const float*)d_in[0];
  const int*   lens  = (const int*)d_in[2];
  const float* Wq    = (const float*)d_in[3];
  const float* bq    = (const float*)d_in[4];
  const float* Wkv   = (const float*)d_in[5];
  const float* bkv   = (const float*)d_in[6];
  const float* Wo    = (const float*)d_in[7];
  const float* bo    = (const float*)d_in[8];
  const float* gamma = (const float*)d_in[9];
  const float* beta  = (const float*)d_in[10];
  float* out = (float*)d_out;

  char* ws = (char*)d_ws;
  __hip_bfloat16* ln  = (__hip_bfloat16*)(ws);
  __hip_bfloat16* qkv = (__hip_bfloat16*)(ws + ((size_t)16 << 20));
  __hip_bfloat16* vt  = (__hip_bfloat16*)(ws + ((size_t)64 << 20));
  __hip_bfloat16* ctx = (__hip_bfloat16*)(ws + ((size_t)80 << 20));
  __hip_bfloat16* wt  = (__hip_bfloat16*)(ws + ((size_t)96 << 20));
  __hip_bfloat16* wot = (__hip_bfloat16*)(ws + ((size_t)102 << 20));

  prep_kernel<<<dim3(9216), dim3(256), 0, stream>>>(
      x, gamma, beta, ln, Wq, Wkv, Wo, wt, wot);
  gemm_qkv<<<dim3(1536), dim3(256), 0, stream>>>(ln, wt, bq, bkv, qkv, vt);
  attn_kernel<<<dim3(1024), dim3(256), 0, stream>>>(qkv, vt, lens, ctx);
  gemm_out<<<dim3(512), dim3(256), 0, stream>>>(ctx, wot, bo, ln, out);
}

// Round 15
// 156.754 us; speedup vs baseline: 1.1143x; 1.0097x over previous
//
#include <hip/hip_runtime.h>
#include <hip/hip_bf16.h>
#include <cstdint>
#include <cmath>

// MultiHeadAttention_38946763440365 : B=4 S=2048 D=1024 H=16 DQ=DV=64
// prep (LN + 3 weight-transposes) -> QKV gemm (128^2, V transposed in-epilogue)
// -> flash attention (swapped-QK in-register softmax, 32 q-rows/wave,
// bh%8==XCD remap, 4 blocks/CU) -> out gemm (+bias+residual, XCD-swizzled).
// Session law (R4/R5/R6/R13): co-residency >= 4 blocks/CU beats per-block
// efficiency for barrier-synced kernels on this chip.
// Workspace map (bytes):
//   [0,16M)    ln    bf16 [8192][1024]   (also the residual)
//   [16M,64M)  qkv   bf16 [8192][3072]   (Q | K | V-part unused)
//   [64M,80M)  vt    bf16 [64][64][2048] (V transposed per (b,h): [dv][s])
//   [80M,96M)  ctx   bf16 [8192][1024]
//   [96M,102M) wt    bf16 [3072][1024]   (Wq^T | Wkv^T)
//   [102M,104M)wot   bf16 [1024][1024]   (Wo^T)

#define DEV static __device__ __forceinline__

typedef float  f32x4 __attribute__((ext_vector_type(4)));
typedef short  s16x8 __attribute__((ext_vector_type(8)));
typedef short  s16x4 __attribute__((ext_vector_type(4)));
typedef __bf16 bf16x8 __attribute__((ext_vector_type(8)));
typedef unsigned int u32x4 __attribute__((ext_vector_type(4)));
typedef unsigned int u32x2 __attribute__((ext_vector_type(2)));

DEV void gload_lds16(const void* g, void* l) {
  __builtin_amdgcn_global_load_lds(
      (const __attribute__((address_space(1))) unsigned int*)g,
      (__attribute__((address_space(3))) unsigned int*)l, 16, 0, 0);
}

DEV bf16x8 ldsv(const void* p) {
  return __builtin_bit_cast(bf16x8, *(const s16x8*)p);
}

DEV f32x4 mfma16(bf16x8 a, bf16x8 b, f32x4 c) {
  return __builtin_amdgcn_mfma_f32_16x16x32_bf16(a, b, c, 0, 0, 0);
}

DEV unsigned short f2b(float f) {
  __hip_bfloat16 h = __float2bfloat16(f);
  return __builtin_bit_cast(unsigned short, h);
}

DEV unsigned int cvt_pk_bf16(float lo, float hi) {
  unsigned int r;
  asm("v_cvt_pk_bf16_f32 %0, %1, %2" : "=v"(r) : "v"(lo), "v"(hi));
  return r;
}

#define MEMFENCE asm volatile("" ::: "memory")

// ---------------------------- prep: LN rows (bid<8192) + weight transposes
__global__ __launch_bounds__(256) void prep_kernel(
    const float* __restrict__ x, const float* __restrict__ gamma,
    const float* __restrict__ beta, __hip_bfloat16* __restrict__ lnout,
    const float* __restrict__ Wq, const float* __restrict__ Wkv,
    const float* __restrict__ Wo,
    __hip_bfloat16* __restrict__ wt, __hip_bfloat16* __restrict__ wot)
{
  __shared__ float smem[64 * 65];
  const int bid = blockIdx.x, t = threadIdx.x;
  if (bid < 8192) {
    const float4 v = ((const float4*)(x + (size_t)bid * 1024))[t];
    float s = v.x + v.y + v.z + v.w;
    float q = v.x * v.x + v.y * v.y + v.z * v.z + v.w * v.w;
#pragma unroll
    for (int m = 1; m < 64; m <<= 1) { s += __shfl_xor(s, m, 64); q += __shfl_xor(q, m, 64); }
    if ((t & 63) == 0) { smem[t >> 6] = s; smem[4 + (t >> 6)] = q; }
    __syncthreads();
    s = smem[0] + smem[1] + smem[2] + smem[3];
    q = smem[4] + smem[5] + smem[6] + smem[7];
    const float mu = s * (1.f / 1024.f);
    const float var = q * (1.f / 1024.f) - mu * mu;
    const float rs = rsqrtf(var + 1e-3f);
    const float4 g = ((const float4*)gamma)[t];
    const float4 bt = ((const float4*)beta)[t];
    s16x4 o;
    o[0] = (short)f2b((v.x - mu) * rs * g.x + bt.x);
    o[1] = (short)f2b((v.y - mu) * rs * g.y + bt.y);
    o[2] = (short)f2b((v.z - mu) * rs * g.z + bt.z);
    o[3] = (short)f2b((v.w - mu) * rs * g.w + bt.w);
    *(s16x4*)((short*)lnout + (size_t)bid * 1024 + t * 4) = o;
  } else {
    int u = bid - 8192;
    const float* W; int N; __hip_bfloat16* Wt;
    if (u < 256)      { W = Wq;  N = 1024; Wt = wt; }
    else if (u < 768) { W = Wkv; N = 2048; Wt = wt + (size_t)1024 * 1024; u -= 256; }
    else              { W = Wo;  N = 1024; Wt = wot; u -= 768; }
    const int k0 = (u & 15) * 64, n0 = (u >> 4) * 64;
    float (*tile)[65] = (float(*)[65])smem;
#pragma unroll
    for (int p = 0; p < 4; ++p) {
      int r = p * 16 + (t >> 4), c4 = (t & 15) * 4;
      float4 v = *(const float4*)(W + (size_t)(k0 + r) * N + n0 + c4);
      tile[r][c4] = v.x; tile[r][c4 + 1] = v.y; tile[r][c4 + 2] = v.z; tile[r][c4 + 3] = v.w;
    }
    __syncthreads();
#pragma unroll
    for (int p = 0; p < 4; ++p) {
      int n = p * 16 + (t >> 4), kc = (t & 15) * 4;
      s16x4 o;
      o[0] = (short)f2b(tile[kc][n]);     o[1] = (short)f2b(tile[kc + 1][n]);
      o[2] = (short)f2b(tile[kc + 2][n]); o[3] = (short)f2b(tile[kc + 3][n]);
      *(s16x4*)((short*)Wt + (size_t)(n0 + n) * 1024 + k0 + kc) = o;
    }
  }
}

// ------------------------- QKV GEMM: 128^2 m97-structure, XCD-swizzled 1-D grid
// Q/K tiles (col0 < 2048) -> qkv.  V tiles (col0 >= 2048) -> transposed in LDS
// and written straight to vt [bh][dv][s].
__global__ __launch_bounds__(256, 2) void gemm_qkv(
    const __hip_bfloat16* __restrict__ A, const __hip_bfloat16* __restrict__ Bt,
    const float* __restrict__ bias0, const float* __restrict__ bias1,
    __hip_bfloat16* __restrict__ outb, __hip_bfloat16* __restrict__ vt)
{
  __shared__ __align__(16) short smem[2 * 128 * 64];   // sA | sB (32KB)
  short* sA = smem;
  short* sB = smem + 128 * 64;
  const int t = threadIdx.x, l = t & 63, w = t >> 6;
  const int wr = w >> 1, wc = w & 1, lr = l & 15, lg = l >> 4;
  int lin = (int)blockIdx.x;
  lin = (lin & 7) * 192 + (lin >> 3);            // bijective: 1536 = 8 * 192
  const int bx = lin % 24, by = lin / 24;
  const int row0 = by * 128, col0 = bx * 128;
  f32x4 acc[4][4] = {};

  for (int kt = 0; kt < 1024; kt += 64) {
#pragma unroll
    for (int p = 0; p < 4; ++p) {
      const int L = p * 4096 + t * 16;
      const int r = L >> 7, c = ((L >> 4) & 7) ^ (r & 7);
      gload_lds16((const char*)A + ((size_t)(row0 + r) * 1024 + kt + c * 8) * 2, (char*)sA + L);
    }
#pragma unroll
    for (int p = 0; p < 4; ++p) {
      const int L = p * 4096 + t * 16;
      const int r = L >> 7, c = ((L >> 4) & 7) ^ (r & 7);
      gload_lds16((const char*)Bt + ((size_t)(col0 + r) * 1024 + kt + c * 8) * 2, (char*)sB + L);
    }
    __syncthreads();

    bf16x8 af[4][2], bfr[4][2];
#pragma unroll
    for (int mb = 0; mb < 4; ++mb) {
      const int ar = wr * 64 + mb * 16 + lr;
#pragma unroll
      for (int kk = 0; kk < 2; ++kk)
        af[mb][kk] = ldsv((const char*)sA + ar * 128 + (((kk * 4 + lg) ^ (ar & 7)) * 16));
    }
#pragma unroll
    for (int nb = 0; nb < 4; ++nb) {
      const int br = wc * 64 + nb * 16 + lr;
#pragma unroll
      for (int kk = 0; kk < 2; ++kk)
        bfr[nb][kk] = ldsv((const char*)sB + br * 128 + (((kk * 4 + lg) ^ (br & 7)) * 16));
    }
#pragma unroll
    for (int kk = 0; kk < 2; ++kk)
#pragma unroll
      for (int mb = 0; mb < 4; ++mb)
#pragma unroll
        for (int nb = 0; nb < 4; ++nb)
          acc[mb][nb] = mfma16(af[mb][kk], bfr[nb][kk], acc[mb][nb]);
    __syncthreads();
  }

  if (col0 < 2048) {
#pragma unroll
    for (int mb = 0; mb < 4; ++mb) {
      const int rbase = row0 + wr * 64 + mb * 16 + lg * 4;
#pragma unroll
      for (int nb = 0; nb < 4; ++nb) {
        const int col = col0 + wc * 64 + nb * 16 + lr;
        const float bias = (col < 1024) ? bias0[col] : bias1[col - 1024];
#pragma unroll
        for (int jr = 0; jr < 4; ++jr)
          outb[(size_t)(rbase + jr) * 3072 + col] = __float2bfloat16(acc[mb][nb][jr] + bias);
      }
    }
  } else {
#pragma unroll
    for (int mb = 0; mb < 4; ++mb) {
      const int rl = wr * 64 + mb * 16 + lg * 4;
#pragma unroll
      for (int nb = 0; nb < 4; ++nb) {
        const int cl = wc * 64 + nb * 16 + lr;
        const float bias = bias1[col0 + cl - 1024];
        s16x4 pk;
#pragma unroll
        for (int jr = 0; jr < 4; ++jr)
          pk[jr] = (short)f2b(acc[mb][nb][jr] + bias);
        *(s16x4*)(&smem[cl * 128 + (rl ^ ((cl & 7) << 3))]) = pk;
      }
    }
    __syncthreads();
    const int b = row0 >> 11, s_in0 = row0 & 2047;
#pragma unroll
    for (int i = 0; i < 8; ++i) {
      const int cl = i * 16 + (t >> 4);
      const int rc = (t & 15) * 8;
      s16x8 v = *(const s16x8*)(&smem[cl * 128 + (rc ^ ((cl & 7) << 3))]);
      const int vcol = col0 - 2048 + cl;
      const int h = vcol >> 6, dv = vcol & 63;
      *(s16x8*)((short*)vt + ((size_t)((b * 16 + h) * 64 + dv)) * 2048 + s_in0 + rc) = v;
    }
  }
}

// ---------------------- GEMM: out proj (+bias+residual), XCD-swizzled 1-D grid
__global__ __launch_bounds__(256, 2) void gemm_out(
    const __hip_bfloat16* __restrict__ A, const __hip_bfloat16* __restrict__ Bt,
    const float* __restrict__ bias0,
    const __hip_bfloat16* __restrict__ resid, float* __restrict__ outf)
{
  __shared__ __align__(16) short sA[128 * 64];
  __shared__ __align__(16) short sB[128 * 64];
  const int t = threadIdx.x, l = t & 63, w = t >> 6;
  const int wr = w >> 1, wc = w & 1, lr = l & 15, lg = l >> 4;
  int lin = (int)blockIdx.x;
  lin = (lin & 7) * 64 + (lin >> 3);             // bijective: 512 = 8 * 64
  const int row0 = (lin >> 3) * 128, col0 = (lin & 7) * 128;
  f32x4 acc[4][4] = {};

  for (int kt = 0; kt < 1024; kt += 64) {
#pragma unroll
    for (int p = 0; p < 4; ++p) {
      const int L = p * 4096 + t * 16;
      const int r = L >> 7, c = ((L >> 4) & 7) ^ (r & 7);
      gload_lds16((const char*)A + ((size_t)(row0 + r) * 1024 + kt + c * 8) * 2, (char*)sA + L);
    }
#pragma unroll
    for (int p = 0; p < 4; ++p) {
      const int L = p * 4096 + t * 16;
      const int r = L >> 7, c = ((L >> 4) & 7) ^ (r & 7);
      gload_lds16((const char*)Bt + ((size_t)(col0 + r) * 1024 + kt + c * 8) * 2, (char*)sB + L);
    }
    __syncthreads();

    bf16x8 af[4][2], bfr[4][2];
#pragma unroll
    for (int mb = 0; mb < 4; ++mb) {
      const int ar = wr * 64 + mb * 16 + lr;
#pragma unroll
      for (int kk = 0; kk < 2; ++kk)
        af[mb][kk] = ldsv((const char*)sA + ar * 128 + (((kk * 4 + lg) ^ (ar & 7)) * 16));
    }
#pragma unroll
    for (int nb = 0; nb < 4; ++nb) {
      const int br = wc * 64 + nb * 16 + lr;
#pragma unroll
      for (int kk = 0; kk < 2; ++kk)
        bfr[nb][kk] = ldsv((const char*)sB + br * 128 + (((kk * 4 + lg) ^ (br & 7)) * 16));
    }
#pragma unroll
    for (int kk = 0; kk < 2; ++kk)
#pragma unroll
      for (int mb = 0; mb < 4; ++mb)
#pragma unroll
        for (int nb = 0; nb < 4; ++nb)
          acc[mb][nb] = mfma16(af[mb][kk], bfr[nb][kk], acc[mb][nb]);
    __syncthreads();
  }

#pragma unroll
  for (int mb = 0; mb < 4; ++mb) {
    const int rbase = row0 + wr * 64 + mb * 16 + lg * 4;
#pragma unroll
    for (int nb = 0; nb < 4; ++nb) {
      const int col = col0 + wc * 64 + nb * 16 + lr;
      const float bias = bias0[col];
#pragma unroll
      for (int jr = 0; jr < 4; ++jr) {
        const size_t idx = (size_t)(rbase + jr) * 1024 + col;
        outf[idx] = acc[mb][nb][jr] + bias + __bfloat162float(resid[idx]);
      }
    }
  }
}

// ----------------------------------------------------------- flash attention
// R12-verified: 1-D grid 1024 (4 blocks/CU), bh%8 == XCD (per-XCD K/V panels
// fit L2). 4 waves x 32 q-rows; KVBLK=64; swapped-QK in-register softmax.
// Epilogue: packed b64 LDS writes via v_cvt_pk_bf16_f32 (same bytes, 4x fewer ops).
__global__ __launch_bounds__(256, 4) void attn_kernel(
    const __hip_bfloat16* __restrict__ qkv, const __hip_bfloat16* __restrict__ vt,
    const int* __restrict__ lens, __hip_bfloat16* __restrict__ ctx)
{
  __shared__ __align__(16) short sK[2][64 * 64];
  __shared__ __align__(16) short sV[2][64 * 64];
  const int t = threadIdx.x, l = t & 63, w = t >> 6;
  const int lr = l & 15, lg = l >> 4;
  const int bid = blockIdx.x;
  const int xcd = bid & 7, j = bid >> 3;
  const int bh = ((j >> 4) << 3) | xcd;          // bh % 8 == xcd; bijective
  const int qb = j & 15;
  const int b = bh >> 4, h = bh & 15;
  const int q0 = qb * 128 + w * 32;
  const int len = lens[b];
  const float NEG = -__builtin_inff();
  const float QSC = 0.18033688f;  // 0.125 * log2(e)

  bf16x8 qf[2][2];
#pragma unroll
  for (int mbt = 0; mbt < 2; ++mbt)
#pragma unroll
    for (int kk = 0; kk < 2; ++kk) {
      bf16x8 r = ldsv((const char*)qkv +
          ((size_t)(b * 2048 + q0 + mbt * 16 + lr) * 3072 + h * 64 + kk * 32 + lg * 8) * 2);
#pragma unroll
      for (int e = 0; e < 8; ++e) qf[mbt][kk][e] = (__bf16)((float)r[e] * QSC);
    }

  f32x4 o[4][2] = {};
  float mrun[2] = {NEG, NEG}, ssum[2] = {0.f, 0.f};

  auto stage = [&](short* dK, short* dV, int kv0) {
#pragma unroll
    for (int p = 0; p < 2; ++p) {
      const int L = p * 4096 + t * 16;
      const int r = L >> 7, c = ((L >> 4) & 7) ^ (r & 7);
      gload_lds16((const char*)qkv +
          ((size_t)(b * 2048 + kv0 + r) * 3072 + 1024 + h * 64 + c * 8) * 2, (char*)dK + L);
    }
#pragma unroll
    for (int p = 0; p < 2; ++p) {
      const int L = p * 4096 + t * 16;
      const int r = L >> 7, c = ((L >> 4) & 7) ^ (r & 7);
      gload_lds16((const char*)vt +
          ((size_t)(bh * 64 + r) * 2048 + kv0 + c * 8) * 2, (char*)dV + L);
    }
  };

  const int nt = (len + 63) >> 6;
  short* curK = sK[0]; short* nxtK = sK[1];
  short* curV = sV[0]; short* nxtV = sV[1];
  stage(curK, curV, 0);

  const int srcA = (lg & 1) * 32 + lr;
  const int srcB = srcA + 16;

  for (int ti = 0; ti < nt; ++ti) {
    const int kv0 = ti * 64;
    if (ti + 1 < nt) {
      stage(nxtK, nxtV, kv0 + 64);
      asm volatile("s_waitcnt vmcnt(4)" ::: "memory");
    } else {
      asm volatile("s_waitcnt vmcnt(0)" ::: "memory");
    }
    MEMFENCE; __builtin_amdgcn_s_barrier(); MEMFENCE;

    f32x4 sf[2][4] = {};
    __builtin_amdgcn_s_setprio(1);
#pragma unroll
    for (int kk = 0; kk < 2; ++kk) {
      bf16x8 ak[4];
#pragma unroll
      for (int nbt = 0; nbt < 4; ++nbt) {
        const int br = nbt * 16 + lr;
        ak[nbt] = ldsv((const char*)curK + br * 128 + (((kk * 4 + lg) ^ (br & 7)) * 16));
      }
#pragma unroll
      for (int mbt = 0; mbt < 2; ++mbt)
#pragma unroll
        for (int nbt = 0; nbt < 4; ++nbt)
          sf[mbt][nbt] = mfma16(ak[nbt], qf[mbt][kk], sf[mbt][nbt]);
    }
    __builtin_amdgcn_s_setprio(0);

    if (kv0 + 64 > len) {
#pragma unroll
      for (int nbt = 0; nbt < 4; ++nbt)
#pragma unroll
        for (int jr = 0; jr < 4; ++jr)
          if (kv0 + nbt * 16 + lg * 4 + jr >= len) {
            sf[0][nbt][jr] = NEG;
            sf[1][nbt][jr] = NEG;
          }
    }

    float rm[2];
#pragma unroll
    for (int mbt = 0; mbt < 2; ++mbt) {
      f32x4 m4 = sf[mbt][0];
      m4 = __builtin_elementwise_max(m4, sf[mbt][1]);
      m4 = __builtin_elementwise_max(m4, sf[mbt][2]);
      m4 = __builtin_elementwise_max(m4, sf[mbt][3]);
      float m0 = fmaxf(fmaxf(m4[0], m4[1]), fmaxf(m4[2], m4[3]));
      m0 = fmaxf(m0, __shfl_xor(m0, 16, 64));
      m0 = fmaxf(m0, __shfl_xor(m0, 32, 64));
      rm[mbt] = m0;
    }
    const bool need = (rm[0] > mrun[0] + 3.f) || (rm[1] > mrun[1] + 3.f);
    if (__any(need)) {
#pragma unroll
      for (int mbt = 0; mbt < 2; ++mbt) {
        const float mnew = fmaxf(mrun[mbt], rm[mbt]);
        const float corr = __builtin_amdgcn_exp2f(mrun[mbt] - mnew);
        mrun[mbt] = mnew;
        ssum[mbt] *= corr;
#pragma unroll
        for (int nbt2 = 0; nbt2 < 4; ++nbt2) o[nbt2][mbt] *= corr;
      }
    }
    unsigned int W0[2][4], W1[2][4];
#pragma unroll
    for (int mbt = 0; mbt < 2; ++mbt) {
      f32x4 ts = {0.f, 0.f, 0.f, 0.f};
#pragma unroll
      for (int nbt = 0; nbt < 4; ++nbt) {
        f32x4 pe;
#pragma unroll
        for (int jr = 0; jr < 4; ++jr)
          pe[jr] = __builtin_amdgcn_exp2f(sf[mbt][nbt][jr] - mrun[mbt]);
        ts += pe;
        W0[mbt][nbt] = cvt_pk_bf16(pe[0], pe[1]);
        W1[mbt][nbt] = cvt_pk_bf16(pe[2], pe[3]);
      }
      ssum[mbt] += (ts[0] + ts[1]) + (ts[2] + ts[3]);
    }

#pragma unroll
    for (int c = 0; c < 2; ++c) {
      bf16x8 vf[4], pb[2];
#pragma unroll
      for (int nbt2 = 0; nbt2 < 4; ++nbt2) {
        const int vr = nbt2 * 16 + lr;
        vf[nbt2] = ldsv((const char*)curV + vr * 128 + (((c * 4 + lg) ^ (vr & 7)) * 16));
      }
#pragma unroll
      for (int mbt = 0; mbt < 2; ++mbt) {
        const unsigned int selW0 = (lg & 2) ? W0[mbt][2 * c + 1] : W0[mbt][2 * c];
        const unsigned int selW1 = (lg & 2) ? W1[mbt][2 * c + 1] : W1[mbt][2 * c];
        u32x4 bw;
        bw[0] = __shfl((int)selW0, srcA, 64);
        bw[1] = __shfl((int)selW1, srcA, 64);
        bw[2] = __shfl((int)selW0, srcB, 64);
        bw[3] = __shfl((int)selW1, srcB, 64);
        pb[mbt] = __builtin_bit_cast(bf16x8, bw);
      }
      __builtin_amdgcn_s_setprio(1);
#pragma unroll
      for (int nbt2 = 0; nbt2 < 4; ++nbt2)
#pragma unroll
        for (int mbt = 0; mbt < 2; ++mbt)
          o[nbt2][mbt] = mfma16(vf[nbt2], pb[mbt], o[nbt2][mbt]);
      __builtin_amdgcn_s_setprio(0);
    }

    asm volatile("s_waitcnt lgkmcnt(0)" ::: "memory");
    MEMFENCE; __builtin_amdgcn_s_barrier(); MEMFENCE;
    short* tk = curK; curK = nxtK; nxtK = tk;
    short* tv = curV; curV = nxtV; nxtV = tv;
  }

  float inv[2];
#pragma unroll
  for (int mbt = 0; mbt < 2; ++mbt) {
    float s = ssum[mbt];
    s += __shfl_xor(s, 16, 64);
    s += __shfl_xor(s, 32, 64);
    inv[mbt] = 1.f / s;
  }
  // epilogue: packed b64 LDS writes (cvt_pk pairs; jr-consecutive, 8B-aligned)
  char* eb = (char*)sK + w * 4352;   // 32 rows x 68 shorts (136 B stride)
#pragma unroll
  for (int mbt = 0; mbt < 2; ++mbt)
#pragma unroll
    for (int nbt2 = 0; nbt2 < 4; ++nbt2) {
      u32x2 pk;
      pk[0] = cvt_pk_bf16(o[nbt2][mbt][0] * inv[mbt], o[nbt2][mbt][1] * inv[mbt]);
      pk[1] = cvt_pk_bf16(o[nbt2][mbt][2] * inv[mbt], o[nbt2][mbt][3] * inv[mbt]);
      *(u32x2*)(eb + (mbt * 16 + lr) * 136 + nbt2 * 32 + lg * 8) = pk;
    }
  asm volatile("s_waitcnt lgkmcnt(0)" ::: "memory");
  __builtin_amdgcn_sched_barrier(0);
  const int qi = l >> 1, half = l & 1;
#pragma unroll
  for (int i = 0; i < 4; ++i) {
    s16x8 v = *(const s16x8*)(eb + qi * 136 + half * 64 + i * 16);
    *(s16x8*)((short*)ctx + (size_t)(b * 2048 + q0 + qi) * 1024 + h * 64 + half * 32 + i * 8) = v;
  }
}

// ------------------------------------------------------------------- launch
extern "C" void kernel_launch(void* const* d_in, const int* in_sizes, int n_in,
                              void* d_out, int out_size, void* d_ws, size_t ws_size,
                              hipStream_t stream)
{
  const float* x     = (const float*)d_in[0];
  const int*   lens  = (const int*)d_in[2];
  const float* Wq    = (const float*)d_in[3];
  const float* bq    = (const float*)d_in[4];
  const float* Wkv   = (const float*)d_in[5];
  const float* bkv   = (const float*)d_in[6];
  const float* Wo    = (const float*)d_in[7];
  const float* bo    = (const float*)d_in[8];
  const float* gamma = (const float*)d_in[9];
  const float* beta  = (const float*)d_in[10];
  float* out = (float*)d_out;

  char* ws = (char*)d_ws;
  __hip_bfloat16* ln  = (__hip_bfloat16*)(ws);
  __hip_bfloat16* qkv = (__hip_bfloat16*)(ws + ((size_t)16 << 20));
  __hip_bfloat16* vt  = (__hip_bfloat16*)(ws + ((size_t)64 << 20));
  __hip_bfloat16* ctx = (__hip_bfloat16*)(ws + ((size_t)80 << 20));
  __hip_bfloat16* wt  = (__hip_bfloat16*)(ws + ((size_t)96 << 20));
  __hip_bfloat16* wot = (__hip_bfloat16*)(ws + ((size_t)102 << 20));

  prep_kernel<<<dim3(9216), dim3(256), 0, stream>>>(
      x, gamma, beta, ln, Wq, Wkv, Wo, wt, wot);
  gemm_qkv<<<dim3(1536), dim3(256), 0, stream>>>(ln, wt, bq, bkv, qkv, vt);
  attn_kernel<<<dim3(1024), dim3(256), 0, stream>>>(qkv, vt, lens, ctx);
  gemm_out<<<dim3(512), dim3(256), 0, stream>>>(ctx, wot, bo, ln, out);
}

// Round 16
// 146.054 us; speedup vs baseline: 1.1959x; 1.0733x over previous
//
#include <hip/hip_runtime.h>
#include <hip/hip_bf16.h>
#include <cstdint>
#include <cmath>

// MultiHeadAttention_38946763440365 : B=4 S=2048 D=1024 H=16 DQ=DV=64
// prep (LN + 3 weight-transposes) -> QKV gemm (128^2, V transposed in-epilogue,
// K/V tiles beyond ceil(len/64)*64 SKIPPED -- attn never reads them) -> flash
// attention (swapped-QK in-register softmax, bh%8==XCD remap, 4 blocks/CU)
// -> out gemm (+bias+residual, XCD-swizzled).
// Session law (R4/R5/R6/R13): co-residency >= 4 blocks/CU beats per-block
// efficiency for barrier-synced kernels on this chip.
// Workspace map (bytes):
//   [0,16M)    ln    bf16 [8192][1024]   (also the residual)
//   [16M,64M)  qkv   bf16 [8192][3072]   (Q | K | V-part unused)
//   [64M,80M)  vt    bf16 [64][64][2048] (V transposed per (b,h): [dv][s])
//   [80M,96M)  ctx   bf16 [8192][1024]
//   [96M,102M) wt    bf16 [3072][1024]   (Wq^T | Wkv^T)
//   [102M,104M)wot   bf16 [1024][1024]   (Wo^T)

#define DEV static __device__ __forceinline__

typedef float  f32x4 __attribute__((ext_vector_type(4)));
typedef short  s16x8 __attribute__((ext_vector_type(8)));
typedef short  s16x4 __attribute__((ext_vector_type(4)));
typedef __bf16 bf16x8 __attribute__((ext_vector_type(8)));
typedef unsigned int u32x4 __attribute__((ext_vector_type(4)));
typedef unsigned int u32x2 __attribute__((ext_vector_type(2)));

DEV void gload_lds16(const void* g, void* l) {
  __builtin_amdgcn_global_load_lds(
      (const __attribute__((address_space(1))) unsigned int*)g,
      (__attribute__((address_space(3))) unsigned int*)l, 16, 0, 0);
}

DEV bf16x8 ldsv(const void* p) {
  return __builtin_bit_cast(bf16x8, *(const s16x8*)p);
}

DEV f32x4 mfma16(bf16x8 a, bf16x8 b, f32x4 c) {
  return __builtin_amdgcn_mfma_f32_16x16x32_bf16(a, b, c, 0, 0, 0);
}

DEV unsigned short f2b(float f) {
  __hip_bfloat16 h = __float2bfloat16(f);
  return __builtin_bit_cast(unsigned short, h);
}

DEV unsigned int cvt_pk_bf16(float lo, float hi) {
  unsigned int r;
  asm("v_cvt_pk_bf16_f32 %0, %1, %2" : "=v"(r) : "v"(lo), "v"(hi));
  return r;
}

#define MEMFENCE asm volatile("" ::: "memory")

// ---------------------------- prep: LN rows (bid<8192) + weight transposes
__global__ __launch_bounds__(256) void prep_kernel(
    const float* __restrict__ x, const float* __restrict__ gamma,
    const float* __restrict__ beta, __hip_bfloat16* __restrict__ lnout,
    const float* __restrict__ Wq, const float* __restrict__ Wkv,
    const float* __restrict__ Wo,
    __hip_bfloat16* __restrict__ wt, __hip_bfloat16* __restrict__ wot)
{
  __shared__ float smem[64 * 65];
  const int bid = blockIdx.x, t = threadIdx.x;
  if (bid < 8192) {
    const float4 v = ((const float4*)(x + (size_t)bid * 1024))[t];
    float s = v.x + v.y + v.z + v.w;
    float q = v.x * v.x + v.y * v.y + v.z * v.z + v.w * v.w;
#pragma unroll
    for (int m = 1; m < 64; m <<= 1) { s += __shfl_xor(s, m, 64); q += __shfl_xor(q, m, 64); }
    if ((t & 63) == 0) { smem[t >> 6] = s; smem[4 + (t >> 6)] = q; }
    __syncthreads();
    s = smem[0] + smem[1] + smem[2] + smem[3];
    q = smem[4] + smem[5] + smem[6] + smem[7];
    const float mu = s * (1.f / 1024.f);
    const float var = q * (1.f / 1024.f) - mu * mu;
    const float rs = rsqrtf(var + 1e-3f);
    const float4 g = ((const float4*)gamma)[t];
    const float4 bt = ((const float4*)beta)[t];
    s16x4 o;
    o[0] = (short)f2b((v.x - mu) * rs * g.x + bt.x);
    o[1] = (short)f2b((v.y - mu) * rs * g.y + bt.y);
    o[2] = (short)f2b((v.z - mu) * rs * g.z + bt.z);
    o[3] = (short)f2b((v.w - mu) * rs * g.w + bt.w);
    *(s16x4*)((short*)lnout + (size_t)bid * 1024 + t * 4) = o;
  } else {
    int u = bid - 8192;
    const float* W; int N; __hip_bfloat16* Wt;
    if (u < 256)      { W = Wq;  N = 1024; Wt = wt; }
    else if (u < 768) { W = Wkv; N = 2048; Wt = wt + (size_t)1024 * 1024; u -= 256; }
    else              { W = Wo;  N = 1024; Wt = wot; u -= 768; }
    const int k0 = (u & 15) * 64, n0 = (u >> 4) * 64;
    float (*tile)[65] = (float(*)[65])smem;
#pragma unroll
    for (int p = 0; p < 4; ++p) {
      int r = p * 16 + (t >> 4), c4 = (t & 15) * 4;
      float4 v = *(const float4*)(W + (size_t)(k0 + r) * N + n0 + c4);
      tile[r][c4] = v.x; tile[r][c4 + 1] = v.y; tile[r][c4 + 2] = v.z; tile[r][c4 + 3] = v.w;
    }
    __syncthreads();
#pragma unroll
    for (int p = 0; p < 4; ++p) {
      int n = p * 16 + (t >> 4), kc = (t & 15) * 4;
      s16x4 o;
      o[0] = (short)f2b(tile[kc][n]);     o[1] = (short)f2b(tile[kc + 1][n]);
      o[2] = (short)f2b(tile[kc + 2][n]); o[3] = (short)f2b(tile[kc + 3][n]);
      *(s16x4*)((short*)Wt + (size_t)(n0 + n) * 1024 + k0 + kc) = o;
    }
  }
}

// ------------------------- QKV GEMM: 128^2 m97-structure, XCD-swizzled 1-D grid
// Q/K tiles (col0 < 2048) -> qkv.  V tiles (col0 >= 2048) -> transposed in LDS
// and written straight to vt [bh][dv][s].  K/V tiles whose 128-row span lies
// entirely past ceil(len[b]/64)*64 are skipped: attn's KV loop never reads them.
__global__ __launch_bounds__(256, 2) void gemm_qkv(
    const __hip_bfloat16* __restrict__ A, const __hip_bfloat16* __restrict__ Bt,
    const float* __restrict__ bias0, const float* __restrict__ bias1,
    const int* __restrict__ lens,
    __hip_bfloat16* __restrict__ outb, __hip_bfloat16* __restrict__ vt)
{
  __shared__ __align__(16) short smem[2 * 128 * 64];   // sA | sB (32KB)
  short* sA = smem;
  short* sB = smem + 128 * 64;
  const int t = threadIdx.x, l = t & 63, w = t >> 6;
  const int wr = w >> 1, wc = w & 1, lr = l & 15, lg = l >> 4;
  int lin = (int)blockIdx.x;
  lin = (lin & 7) * 192 + (lin >> 3);            // bijective: 1536 = 8 * 192
  const int bx = lin % 24, by = lin / 24;
  const int row0 = by * 128, col0 = bx * 128;

  // dead-tile skip (block-uniform): K/V columns, rows past the attn read-set
  if (col0 >= 1024) {
    const int lim = (lens[row0 >> 11] + 63) & ~63;   // ceil(len/64)*64
    if ((row0 & 2047) >= lim) return;
  }

  f32x4 acc[4][4] = {};

  for (int kt = 0; kt < 1024; kt += 64) {
#pragma unroll
    for (int p = 0; p < 4; ++p) {
      const int L = p * 4096 + t * 16;
      const int r = L >> 7, c = ((L >> 4) & 7) ^ (r & 7);
      gload_lds16((const char*)A + ((size_t)(row0 + r) * 1024 + kt + c * 8) * 2, (char*)sA + L);
    }
#pragma unroll
    for (int p = 0; p < 4; ++p) {
      const int L = p * 4096 + t * 16;
      const int r = L >> 7, c = ((L >> 4) & 7) ^ (r & 7);
      gload_lds16((const char*)Bt + ((size_t)(col0 + r) * 1024 + kt + c * 8) * 2, (char*)sB + L);
    }
    __syncthreads();

    bf16x8 af[4][2], bfr[4][2];
#pragma unroll
    for (int mb = 0; mb < 4; ++mb) {
      const int ar = wr * 64 + mb * 16 + lr;
#pragma unroll
      for (int kk = 0; kk < 2; ++kk)
        af[mb][kk] = ldsv((const char*)sA + ar * 128 + (((kk * 4 + lg) ^ (ar & 7)) * 16));
    }
#pragma unroll
    for (int nb = 0; nb < 4; ++nb) {
      const int br = wc * 64 + nb * 16 + lr;
#pragma unroll
      for (int kk = 0; kk < 2; ++kk)
        bfr[nb][kk] = ldsv((const char*)sB + br * 128 + (((kk * 4 + lg) ^ (br & 7)) * 16));
    }
#pragma unroll
    for (int kk = 0; kk < 2; ++kk)
#pragma unroll
      for (int mb = 0; mb < 4; ++mb)
#pragma unroll
        for (int nb = 0; nb < 4; ++nb)
          acc[mb][nb] = mfma16(af[mb][kk], bfr[nb][kk], acc[mb][nb]);
    __syncthreads();
  }

  if (col0 < 2048) {
#pragma unroll
    for (int mb = 0; mb < 4; ++mb) {
      const int rbase = row0 + wr * 64 + mb * 16 + lg * 4;
#pragma unroll
      for (int nb = 0; nb < 4; ++nb) {
        const int col = col0 + wc * 64 + nb * 16 + lr;
        const float bias = (col < 1024) ? bias0[col] : bias1[col - 1024];
#pragma unroll
        for (int jr = 0; jr < 4; ++jr)
          outb[(size_t)(rbase + jr) * 3072 + col] = __float2bfloat16(acc[mb][nb][jr] + bias);
      }
    }
  } else {
#pragma unroll
    for (int mb = 0; mb < 4; ++mb) {
      const int rl = wr * 64 + mb * 16 + lg * 4;
#pragma unroll
      for (int nb = 0; nb < 4; ++nb) {
        const int cl = wc * 64 + nb * 16 + lr;
        const float bias = bias1[col0 + cl - 1024];
        s16x4 pk;
#pragma unroll
        for (int jr = 0; jr < 4; ++jr)
          pk[jr] = (short)f2b(acc[mb][nb][jr] + bias);
        *(s16x4*)(&smem[cl * 128 + (rl ^ ((cl & 7) << 3))]) = pk;
      }
    }
    __syncthreads();
    const int b = row0 >> 11, s_in0 = row0 & 2047;
#pragma unroll
    for (int i = 0; i < 8; ++i) {
      const int cl = i * 16 + (t >> 4);
      const int rc = (t & 15) * 8;
      s16x8 v = *(const s16x8*)(&smem[cl * 128 + (rc ^ ((cl & 7) << 3))]);
      const int vcol = col0 - 2048 + cl;
      const int h = vcol >> 6, dv = vcol & 63;
      *(s16x8*)((short*)vt + ((size_t)((b * 16 + h) * 64 + dv)) * 2048 + s_in0 + rc) = v;
    }
  }
}

// ---------------------- GEMM: out proj (+bias+residual), XCD-swizzled 1-D grid
__global__ __launch_bounds__(256, 2) void gemm_out(
    const __hip_bfloat16* __restrict__ A, const __hip_bfloat16* __restrict__ Bt,
    const float* __restrict__ bias0,
    const __hip_bfloat16* __restrict__ resid, float* __restrict__ outf)
{
  __shared__ __align__(16) short sA[128 * 64];
  __shared__ __align__(16) short sB[128 * 64];
  const int t = threadIdx.x, l = t & 63, w = t >> 6;
  const int wr = w >> 1, wc = w & 1, lr = l & 15, lg = l >> 4;
  int lin = (int)blockIdx.x;
  lin = (lin & 7) * 64 + (lin >> 3);             // bijective: 512 = 8 * 64
  const int row0 = (lin >> 3) * 128, col0 = (lin & 7) * 128;
  f32x4 acc[4][4] = {};

  for (int kt = 0; kt < 1024; kt += 64) {
#pragma unroll
    for (int p = 0; p < 4; ++p) {
      const int L = p * 4096 + t * 16;
      const int r = L >> 7, c = ((L >> 4) & 7) ^ (r & 7);
      gload_lds16((const char*)A + ((size_t)(row0 + r) * 1024 + kt + c * 8) * 2, (char*)sA + L);
    }
#pragma unroll
    for (int p = 0; p < 4; ++p) {
      const int L = p * 4096 + t * 16;
      const int r = L >> 7, c = ((L >> 4) & 7) ^ (r & 7);
      gload_lds16((const char*)Bt + ((size_t)(col0 + r) * 1024 + kt + c * 8) * 2, (char*)sB + L);
    }
    __syncthreads();

    bf16x8 af[4][2], bfr[4][2];
#pragma unroll
    for (int mb = 0; mb < 4; ++mb) {
      const int ar = wr * 64 + mb * 16 + lr;
#pragma unroll
      for (int kk = 0; kk < 2; ++kk)
        af[mb][kk] = ldsv((const char*)sA + ar * 128 + (((kk * 4 + lg) ^ (ar & 7)) * 16));
    }
#pragma unroll
    for (int nb = 0; nb < 4; ++nb) {
      const int br = wc * 64 + nb * 16 + lr;
#pragma unroll
      for (int kk = 0; kk < 2; ++kk)
        bfr[nb][kk] = ldsv((const char*)sB + br * 128 + (((kk * 4 + lg) ^ (br & 7)) * 16));
    }
#pragma unroll
    for (int kk = 0; kk < 2; ++kk)
#pragma unroll
      for (int mb = 0; mb < 4; ++mb)
#pragma unroll
        for (int nb = 0; nb < 4; ++nb)
          acc[mb][nb] = mfma16(af[mb][kk], bfr[nb][kk], acc[mb][nb]);
    __syncthreads();
  }

#pragma unroll
  for (int mb = 0; mb < 4; ++mb) {
    const int rbase = row0 + wr * 64 + mb * 16 + lg * 4;
#pragma unroll
    for (int nb = 0; nb < 4; ++nb) {
      const int col = col0 + wc * 64 + nb * 16 + lr;
      const float bias = bias0[col];
#pragma unroll
      for (int jr = 0; jr < 4; ++jr) {
        const size_t idx = (size_t)(rbase + jr) * 1024 + col;
        outf[idx] = acc[mb][nb][jr] + bias + __bfloat162float(resid[idx]);
      }
    }
  }
}

// ----------------------------------------------------------- flash attention
// R15-verified: 1-D grid 1024 (4 blocks/CU), bh%8 == XCD (per-XCD K/V panels
// fit L2). 4 waves x 32 q-rows; KVBLK=64; swapped-QK in-register softmax.
// Epilogue: packed b64 LDS writes via v_cvt_pk_bf16_f32.
__global__ __launch_bounds__(256, 4) void attn_kernel(
    const __hip_bfloat16* __restrict__ qkv, const __hip_bfloat16* __restrict__ vt,
    const int* __restrict__ lens, __hip_bfloat16* __restrict__ ctx)
{
  __shared__ __align__(16) short sK[2][64 * 64];
  __shared__ __align__(16) short sV[2][64 * 64];
  const int t = threadIdx.x, l = t & 63, w = t >> 6;
  const int lr = l & 15, lg = l >> 4;
  const int bid = blockIdx.x;
  const int xcd = bid & 7, j = bid >> 3;
  const int bh = ((j >> 4) << 3) | xcd;          // bh % 8 == xcd; bijective
  const int qb = j & 15;
  const int b = bh >> 4, h = bh & 15;
  const int q0 = qb * 128 + w * 32;
  const int len = lens[b];
  const float NEG = -__builtin_inff();
  const float QSC = 0.18033688f;  // 0.125 * log2(e)

  bf16x8 qf[2][2];
#pragma unroll
  for (int mbt = 0; mbt < 2; ++mbt)
#pragma unroll
    for (int kk = 0; kk < 2; ++kk) {
      bf16x8 r = ldsv((const char*)qkv +
          ((size_t)(b * 2048 + q0 + mbt * 16 + lr) * 3072 + h * 64 + kk * 32 + lg * 8) * 2);
#pragma unroll
      for (int e = 0; e < 8; ++e) qf[mbt][kk][e] = (__bf16)((float)r[e] * QSC);
    }

  f32x4 o[4][2] = {};
  float mrun[2] = {NEG, NEG}, ssum[2] = {0.f, 0.f};

  auto stage = [&](short* dK, short* dV, int kv0) {
#pragma unroll
    for (int p = 0; p < 2; ++p) {
      const int L = p * 4096 + t * 16;
      const int r = L >> 7, c = ((L >> 4) & 7) ^ (r & 7);
      gload_lds16((const char*)qkv +
          ((size_t)(b * 2048 + kv0 + r) * 3072 + 1024 + h * 64 + c * 8) * 2, (char*)dK + L);
    }
#pragma unroll
    for (int p = 0; p < 2; ++p) {
      const int L = p * 4096 + t * 16;
      const int r = L >> 7, c = ((L >> 4) & 7) ^ (r & 7);
      gload_lds16((const char*)vt +
          ((size_t)(bh * 64 + r) * 2048 + kv0 + c * 8) * 2, (char*)dV + L);
    }
  };

  const int nt = (len + 63) >> 6;
  short* curK = sK[0]; short* nxtK = sK[1];
  short* curV = sV[0]; short* nxtV = sV[1];
  stage(curK, curV, 0);

  const int srcA = (lg & 1) * 32 + lr;
  const int srcB = srcA + 16;

  for (int ti = 0; ti < nt; ++ti) {
    const int kv0 = ti * 64;
    if (ti + 1 < nt) {
      stage(nxtK, nxtV, kv0 + 64);
      asm volatile("s_waitcnt vmcnt(4)" ::: "memory");
    } else {
      asm volatile("s_waitcnt vmcnt(0)" ::: "memory");
    }
    MEMFENCE; __builtin_amdgcn_s_barrier(); MEMFENCE;

    f32x4 sf[2][4] = {};
    __builtin_amdgcn_s_setprio(1);
#pragma unroll
    for (int kk = 0; kk < 2; ++kk) {
      bf16x8 ak[4];
#pragma unroll
      for (int nbt = 0; nbt < 4; ++nbt) {
        const int br = nbt * 16 + lr;
        ak[nbt] = ldsv((const char*)curK + br * 128 + (((kk * 4 + lg) ^ (br & 7)) * 16));
      }
#pragma unroll
      for (int mbt = 0; mbt < 2; ++mbt)
#pragma unroll
        for (int nbt = 0; nbt < 4; ++nbt)
          sf[mbt][nbt] = mfma16(ak[nbt], qf[mbt][kk], sf[mbt][nbt]);
    }
    __builtin_amdgcn_s_setprio(0);

    if (kv0 + 64 > len) {
#pragma unroll
      for (int nbt = 0; nbt < 4; ++nbt)
#pragma unroll
        for (int jr = 0; jr < 4; ++jr)
          if (kv0 + nbt * 16 + lg * 4 + jr >= len) {
            sf[0][nbt][jr] = NEG;
            sf[1][nbt][jr] = NEG;
          }
    }

    float rm[2];
#pragma unroll
    for (int mbt = 0; mbt < 2; ++mbt) {
      f32x4 m4 = sf[mbt][0];
      m4 = __builtin_elementwise_max(m4, sf[mbt][1]);
      m4 = __builtin_elementwise_max(m4, sf[mbt][2]);
      m4 = __builtin_elementwise_max(m4, sf[mbt][3]);
      float m0 = fmaxf(fmaxf(m4[0], m4[1]), fmaxf(m4[2], m4[3]));
      m0 = fmaxf(m0, __shfl_xor(m0, 16, 64));
      m0 = fmaxf(m0, __shfl_xor(m0, 32, 64));
      rm[mbt] = m0;
    }
    const bool need = (rm[0] > mrun[0] + 3.f) || (rm[1] > mrun[1] + 3.f);
    if (__any(need)) {
#pragma unroll
      for (int mbt = 0; mbt < 2; ++mbt) {
        const float mnew = fmaxf(mrun[mbt], rm[mbt]);
        const float corr = __builtin_amdgcn_exp2f(mrun[mbt] - mnew);
        mrun[mbt] = mnew;
        ssum[mbt] *= corr;
#pragma unroll
        for (int nbt2 = 0; nbt2 < 4; ++nbt2) o[nbt2][mbt] *= corr;
      }
    }
    unsigned int W0[2][4], W1[2][4];
#pragma unroll
    for (int mbt = 0; mbt < 2; ++mbt) {
      f32x4 ts = {0.f, 0.f, 0.f, 0.f};
#pragma unroll
      for (int nbt = 0; nbt < 4; ++nbt) {
        f32x4 pe;
#pragma unroll
        for (int jr = 0; jr < 4; ++jr)
          pe[jr] = __builtin_amdgcn_exp2f(sf[mbt][nbt][jr] - mrun[mbt]);
        ts += pe;
        W0[mbt][nbt] = cvt_pk_bf16(pe[0], pe[1]);
        W1[mbt][nbt] = cvt_pk_bf16(pe[2], pe[3]);
      }
      ssum[mbt] += (ts[0] + ts[1]) + (ts[2] + ts[3]);
    }

#pragma unroll
    for (int c = 0; c < 2; ++c) {
      bf16x8 vf[4], pb[2];
#pragma unroll
      for (int nbt2 = 0; nbt2 < 4; ++nbt2) {
        const int vr = nbt2 * 16 + lr;
        vf[nbt2] = ldsv((const char*)curV + vr * 128 + (((c * 4 + lg) ^ (vr & 7)) * 16));
      }
#pragma unroll
      for (int mbt = 0; mbt < 2; ++mbt) {
        const unsigned int selW0 = (lg & 2) ? W0[mbt][2 * c + 1] : W0[mbt][2 * c];
        const unsigned int selW1 = (lg & 2) ? W1[mbt][2 * c + 1] : W1[mbt][2 * c];
        u32x4 bw;
        bw[0] = __shfl((int)selW0, srcA, 64);
        bw[1] = __shfl((int)selW1, srcA, 64);
        bw[2] = __shfl((int)selW0, srcB, 64);
        bw[3] = __shfl((int)selW1, srcB, 64);
        pb[mbt] = __builtin_bit_cast(bf16x8, bw);
      }
      __builtin_amdgcn_s_setprio(1);
#pragma unroll
      for (int nbt2 = 0; nbt2 < 4; ++nbt2)
#pragma unroll
        for (int mbt = 0; mbt < 2; ++mbt)
          o[nbt2][mbt] = mfma16(vf[nbt2], pb[mbt], o[nbt2][mbt]);
      __builtin_amdgcn_s_setprio(0);
    }

    asm volatile("s_waitcnt lgkmcnt(0)" ::: "memory");
    MEMFENCE; __builtin_amdgcn_s_barrier(); MEMFENCE;
    short* tk = curK; curK = nxtK; nxtK = tk;
    short* tv = curV; curV = nxtV; nxtV = tv;
  }

  float inv[2];
#pragma unroll
  for (int mbt = 0; mbt < 2; ++mbt) {
    float s = ssum[mbt];
    s += __shfl_xor(s, 16, 64);
    s += __shfl_xor(s, 32, 64);
    inv[mbt] = 1.f / s;
  }
  // epilogue: packed b64 LDS writes (cvt_pk pairs; jr-consecutive, 8B-aligned)
  char* eb = (char*)sK + w * 4352;   // 32 rows x 68 shorts (136 B stride)
#pragma unroll
  for (int mbt = 0; mbt < 2; ++mbt)
#pragma unroll
    for (int nbt2 = 0; nbt2 < 4; ++nbt2) {
      u32x2 pk;
      pk[0] = cvt_pk_bf16(o[nbt2][mbt][0] * inv[mbt], o[nbt2][mbt][1] * inv[mbt]);
      pk[1] = cvt_pk_bf16(o[nbt2][mbt][2] * inv[mbt], o[nbt2][mbt][3] * inv[mbt]);
      *(u32x2*)(eb + (mbt * 16 + lr) * 136 + nbt2 * 32 + lg * 8) = pk;
    }
  asm volatile("s_waitcnt lgkmcnt(0)" ::: "memory");
  __builtin_amdgcn_sched_barrier(0);
  const int qi = l >> 1, half = l & 1;
#pragma unroll
  for (int i = 0; i < 4; ++i) {
    s16x8 v = *(const s16x8*)(eb + qi * 136 + half * 64 + i * 16);
    *(s16x8*)((short*)ctx + (size_t)(b * 2048 + q0 + qi) * 1024 + h * 64 + half * 32 + i * 8) = v;
  }
}

// ------------------------------------------------------------------- launch
extern "C" void kernel_launch(void* const* d_in, const int* in_sizes, int n_in,
                              void* d_out, int out_size, void* d_ws, size_t ws_size,
                              hipStream_t stream)
{
  const float* x     = (const float*)d_in[0];
  const int*   lens  = (const int*)d_in[2];
  const float* Wq    = (const float*)d_in[3];
  const float* bq    = (const float*)d_in[4];
  const float* Wkv   = (const float*)d_in[5];
  const float* bkv   = (const float*)d_in[6];
  const float* Wo    = (const float*)d_in[7];
  const float* bo    = (const float*)d_in[8];
  const float* gamma = (const float*)d_in[9];
  const float* beta  = (const float*)d_in[10];
  float* out = (float*)d_out;

  char* ws = (char*)d_ws;
  __hip_bfloat16* ln  = (__hip_bfloat16*)(ws);
  __hip_bfloat16* qkv = (__hip_bfloat16*)(ws + ((size_t)16 << 20));
  __hip_bfloat16* vt  = (__hip_bfloat16*)(ws + ((size_t)64 << 20));
  __hip_bfloat16* ctx = (__hip_bfloat16*)(ws + ((size_t)80 << 20));
  __hip_bfloat16* wt  = (__hip_bfloat16*)(ws + ((size_t)96 << 20));
  __hip_bfloat16* wot = (__hip_bfloat16*)(ws + ((size_t)102 << 20));

  prep_kernel<<<dim3(9216), dim3(256), 0, stream>>>(
      x, gamma, beta, ln, Wq, Wkv, Wo, wt, wot);
  gemm_qkv<<<dim3(1536), dim3(256), 0, stream>>>(ln, wt, bq, bkv, lens, qkv, vt);
  attn_kernel<<<dim3(1024), dim3(256), 0, stream>>>(qkv, vt, lens, ctx);
  gemm_out<<<dim3(512), dim3(256), 0, stream>>>(ctx, wot, bo, ln, out);
}